// Round 1
// baseline (816.923 us; speedup 1.0000x reference)
//
#include <hip/hip_runtime.h>
#include <cstdint>
#include <cstddef>

typedef __bf16 bf16;
typedef __bf16 bf16x8 __attribute__((ext_vector_type(8)));
typedef __bf16 bf16x4 __attribute__((ext_vector_type(4)));
typedef float  f32x4  __attribute__((ext_vector_type(4)));

#define NB 7
static constexpr int Bq = 2, Sq = 4096, Dm = 1024, Dff = 4096;
static constexpr int Mrows = Bq * Sq;     // 8192
static constexpr int NCH = Sq / 4;        // 1024 chunks per (b,h)
static constexpr int CSW = 464;           // padded prefix-state row width (7 + pad + 7*64)

__device__ __forceinline__ void gload16(const void* g, void* l) {
  __builtin_amdgcn_global_load_lds((__attribute__((address_space(1))) void*)g,
                                   (__attribute__((address_space(3))) void*)l,
                                   16, 0, 0);
}

__device__ __forceinline__ float gelu_f(float x) {
  const float c = 0.79788456080286535588f;
  float z = c * (x + 0.044715f * x * x * x);
  float t = 1.f - 2.f / (__expf(2.f * z) + 1.f);   // tanh(z)
  return 0.5f * x * (1.f + t);
}

// ---------------- f32 -> bf16 convert ----------------
__global__ __launch_bounds__(256) void cvt_kernel(const float* __restrict__ in,
                                                  bf16* __restrict__ out, int n4) {
  int i = blockIdx.x * 256 + threadIdx.x;
  if (i >= n4) return;
  f32x4 v = *(const f32x4*)&in[(size_t)i * 4];
  bf16x4 o;
#pragma unroll
  for (int e = 0; e < 4; ++e) o[e] = (bf16)v[e];
  *(bf16x4*)&out[(size_t)i * 4] = o;
}

// ---------------- LayerNorm (ddof=1, /(std+eps)) -> bf16 ----------------
__global__ __launch_bounds__(256) void ln_kernel(const float* __restrict__ x,
                                                 const float* __restrict__ alpha,
                                                 const float* __restrict__ beta,
                                                 bf16* __restrict__ out) {
  const int row = blockIdx.x, tid = threadIdx.x;
  const float* xr = x + (size_t)row * Dm;
  f32x4 v = *(const f32x4*)&xr[tid * 4];
  float s  = v[0] + v[1] + v[2] + v[3];
  float s2 = v[0]*v[0] + v[1]*v[1] + v[2]*v[2] + v[3]*v[3];
#pragma unroll
  for (int o = 32; o > 0; o >>= 1) { s += __shfl_xor(s, o); s2 += __shfl_xor(s2, o); }
  __shared__ float red[8];
  const int wid = tid >> 6, lane = tid & 63;
  if (lane == 0) { red[wid] = s; red[wid + 4] = s2; }
  __syncthreads();
  s  = red[0] + red[1] + red[2] + red[3];
  s2 = red[4] + red[5] + red[6] + red[7];
  const float mean = s * (1.f / 1024.f);
  float var = (s2 - s * mean) * (1.f / 1023.f);
  var = fmaxf(var, 0.f);
  const float inv = 1.f / (sqrtf(var) + 1e-6f);
  f32x4 a4 = *(const f32x4*)&alpha[tid * 4];
  f32x4 b4 = *(const f32x4*)&beta[tid * 4];
  bf16x4 o4;
#pragma unroll
  for (int e = 0; e < 4; ++e) o4[e] = (bf16)(a4[e] * (v[e] - mean) * inv + b4[e]);
  *(bf16x4*)&out[(size_t)row * Dm + tid * 4] = o4;
}

// ---------------- GEMM: C[M,N] = A[M,K] @ W[N,K]^T, bf16 in, f32 acc ----------------
// MODE 0: out bf16
// MODE 1: +res(f32), out bf16
// MODE 2: +res(f32), out f32
// MODE 3: +bias, gelu, out bf16
// MODE 4: +bias +res(f32), out f32
template <int MODE>
__global__ __launch_bounds__(256) void gemm_bt(
    const bf16* __restrict__ A, const bf16* __restrict__ Bw,
    int M, int N, int K,
    const float* __restrict__ bias, const float* __restrict__ res,
    float* __restrict__ outF, bf16* __restrict__ outB) {
  __shared__ __align__(16) bf16 As[128 * 64];
  __shared__ __align__(16) bf16 Bs[128 * 64];
  const int tid = threadIdx.x;
  const int lane = tid & 63, wid = tid >> 6;
  const int bm = blockIdx.y * 128, bn = blockIdx.x * 128;
  const int wr = (wid >> 1) * 64, wc = (wid & 1) * 64;
  f32x4 acc[4][4] = {};

  const int srow = tid >> 3;
  const int sc = (tid & 7) * 8;
  const bf16* Ab = A  + (size_t)(bm + srow) * K + sc;
  const bf16* Bb = Bw + (size_t)(bn + srow) * K + sc;
  char* AsB = (char*)As + (size_t)wid * 1024;
  char* BsB = (char*)Bs + (size_t)wid * 1024;

  for (int kt = 0; kt < K; kt += 64) {
    __syncthreads();
#pragma unroll
    for (int p = 0; p < 4; ++p) {
      gload16(Ab + (size_t)(p * 32) * K + kt, AsB + p * 4096);
      gload16(Bb + (size_t)(p * 32) * K + kt, BsB + p * 4096);
    }
    __syncthreads();
#pragma unroll
    for (int kk = 0; kk < 2; ++kk) {
      bf16x8 af[4], bfv[4];
      const int ko = kk * 32 + (lane >> 4) * 8;
#pragma unroll
      for (int i = 0; i < 4; ++i)
        af[i] = *(const bf16x8*)&As[(wr + i * 16 + (lane & 15)) * 64 + ko];
#pragma unroll
      for (int j = 0; j < 4; ++j)
        bfv[j] = *(const bf16x8*)&Bs[(wc + j * 16 + (lane & 15)) * 64 + ko];
#pragma unroll
      for (int i = 0; i < 4; ++i)
#pragma unroll
        for (int j = 0; j < 4; ++j)
          acc[i][j] = __builtin_amdgcn_mfma_f32_16x16x32_bf16(af[i], bfv[j], acc[i][j], 0, 0, 0);
    }
  }

#pragma unroll
  for (int i = 0; i < 4; ++i) {
    const int r0 = bm + wr + i * 16 + (lane >> 4) * 4;
#pragma unroll
    for (int j = 0; j < 4; ++j) {
      const int c = bn + wc + j * 16 + (lane & 15);
      float bv = 0.f;
      if (MODE == 3 || MODE == 4) bv = bias[c];
#pragma unroll
      for (int r = 0; r < 4; ++r) {
        const size_t idx = (size_t)(r0 + r) * N + c;
        float v = acc[i][j][r];
        if (MODE == 1 || MODE == 2) v += res[idx];
        if (MODE == 3) v = gelu_f(v + bv);
        if (MODE == 4) v += bv + res[idx];
        if (MODE == 0 || MODE == 1 || MODE == 3) outB[idx] = (bf16)v;
        else outF[idx] = v;
      }
    }
  }
}

// ---------------- Performer: per-chunk sums of kp and kp (x) v ----------------
// grid (S/128, B*H). CS row layout per chunk: [0..6]=sum kp, [8 + n*64 + d]=sum kp*v
__global__ __launch_bounds__(256) void perf_chunks(
    const bf16* __restrict__ kmat, const bf16* __restrict__ vmat,
    const float* __restrict__ omega, float* __restrict__ CS) {
  const int tid = threadIdx.x;
  const int bh = blockIdx.y, b = bh >> 4, h = bh & 15;
  const int s0 = blockIdx.x * 128;
  __shared__ __align__(16) bf16 vs[128][72];
  __shared__ float kps[128][8];
  __shared__ float oms[NB * 64];

  {
    const bf16* vb = vmat + ((size_t)(b * Sq + s0)) * Dm + h * 64;
#pragma unroll
    for (int p = 0; p < 4; ++p) {
      int row = p * 32 + (tid >> 3), c16 = (tid & 7) * 8;
      *(uint4*)&vs[row][c16] = *(const uint4*)&vb[(size_t)row * Dm + c16];
    }
  }
  if (tid < 224) { oms[tid] = omega[tid]; oms[tid + 224] = omega[tid + 224]; }
  __syncthreads();
  {
    const int p = tid >> 1, half = tid & 1;
    const bf16* kr = kmat + ((size_t)(b * Sq + s0 + p)) * Dm + h * 64 + half * 32;
    bf16x8 kv[4];
#pragma unroll
    for (int q = 0; q < 4; ++q) kv[q] = *(const bf16x8*)&kr[q * 8];
    float f[NB];
#pragma unroll
    for (int n = 0; n < NB; ++n) f[n] = 0.f;
#pragma unroll
    for (int d = 0; d < 32; ++d) {
      float kd = (float)kv[d >> 3][d & 7];
#pragma unroll
      for (int n = 0; n < NB; ++n) f[n] += kd * oms[n * 64 + half * 32 + d];
    }
    float sum = 1e-6f;
    float e[NB];
#pragma unroll
    for (int n = 0; n < NB; ++n) {
      float full = f[n] + __shfl_xor(f[n], 1);
      e[n] = __expf(-0.5f * full * full);
      sum += e[n];
    }
    float inv = 1.f / sum;
    if (half == 0) {
#pragma unroll
      for (int n = 0; n < NB; ++n) kps[p][n] = e[n] * inv;
    }
  }
  __syncthreads();
  {
    const int d = tid & 63, w = tid >> 6;
    float* base = CS + ((size_t)bh * NCH + (s0 >> 2)) * CSW;
    for (int cl = w; cl < 32; cl += 4) {
      float vv[4];
#pragma unroll
      for (int i = 0; i < 4; ++i) vv[i] = (float)vs[cl * 4 + i][d];
#pragma unroll
      for (int n = 0; n < NB; ++n) {
        float a = kps[cl*4+0][n]*vv[0] + kps[cl*4+1][n]*vv[1] +
                  kps[cl*4+2][n]*vv[2] + kps[cl*4+3][n]*vv[3];
        base[(size_t)cl * CSW + 8 + n * 64 + d] = a;
      }
    }
    if (tid < 32) {
#pragma unroll
      for (int n = 0; n < NB; ++n)
        base[(size_t)tid * CSW + n] =
            kps[tid*4][n] + kps[tid*4+1][n] + kps[tid*4+2][n] + kps[tid*4+3][n];
      base[(size_t)tid * CSW + 7] = 0.f;
#pragma unroll
      for (int z = 456; z < 464; ++z) base[(size_t)tid * CSW + z] = 0.f;
    }
  }
}

// ---------------- segment-local inclusive scan (128 chunks), write seg totals ----------------
__global__ __launch_bounds__(256) void perf_scan(float* __restrict__ CS, float* __restrict__ segtot) {
  const int bh = blockIdx.y, seg = blockIdx.x;
  float* base = CS + ((size_t)bh * NCH + seg * 128) * CSW;
  const int c0 = threadIdx.x;
  float r0 = 0.f, r1 = 0.f;
#pragma unroll 4
  for (int c = 0; c < 128; ++c) {
    float* row = base + (size_t)c * CSW;
    r0 += row[c0]; row[c0] = r0;
    if (c0 + 256 < CSW) { r1 += row[c0 + 256]; row[c0 + 256] = r1; }
  }
  float* st = segtot + ((size_t)bh * 8 + seg) * CSW;
  st[c0] = r0;
  if (c0 + 256 < CSW) st[c0 + 256] = r1;
}

// ---------------- exclusive scan of the 8 segment totals per (b,h) ----------------
__global__ __launch_bounds__(256) void perf_scan2(float* __restrict__ segtot) {
  const int bh = blockIdx.x;
  const int c0 = threadIdx.x;
  float run0 = 0.f, run1 = 0.f;
#pragma unroll
  for (int s = 0; s < 8; ++s) {
    float* st = segtot + ((size_t)bh * 8 + s) * CSW;
    float t0 = st[c0]; st[c0] = run0; run0 += t0;
    if (c0 + 256 < CSW) { float t1 = st[c0 + 256]; st[c0 + 256] = run1; run1 += t1; }
  }
}

// ---------------- Performer output: qp, num/den -> attn (bf16) ----------------
// grid (S/128, B*H)
__global__ __launch_bounds__(256) void perf_out(
    const bf16* __restrict__ qmat, const float* __restrict__ omega,
    const float* __restrict__ CS, const float* __restrict__ segtot,
    bf16* __restrict__ attn) {
  const int tid = threadIdx.x;
  const int bh = blockIdx.y, b = bh >> 4, h = bh & 15;
  const int s0 = blockIdx.x * 128;
  const int cg0 = s0 >> 2;   // first of 32 chunks
  const int seg = cg0 >> 7;
  __shared__ __align__(16) float Ps[32 * CSW];
  __shared__ float qps[128][8];
  __shared__ float oms[NB * 64];

  {
    const float* src = CS + ((size_t)bh * NCH + cg0) * CSW;
    const float* off = segtot + ((size_t)bh * 8 + seg) * CSW;
    for (int i = tid; i < 32 * CSW / 4; i += 256) {
      f32x4 a = *(const f32x4*)&src[i * 4];
      f32x4 o = *(const f32x4*)&off[(i % (CSW / 4)) * 4];
      a += o;
      *(f32x4*)&Ps[i * 4] = a;
    }
  }
  if (tid < 224) { oms[tid] = omega[tid]; oms[tid + 224] = omega[tid + 224]; }
  __syncthreads();
  {
    const int p = tid >> 1, half = tid & 1;
    const bf16* qr = qmat + ((size_t)(b * Sq + s0 + p)) * Dm + h * 64 + half * 32;
    bf16x8 qv[4];
#pragma unroll
    for (int q = 0; q < 4; ++q) qv[q] = *(const bf16x8*)&qr[q * 8];
    float f[NB];
#pragma unroll
    for (int n = 0; n < NB; ++n) f[n] = 0.f;
#pragma unroll
    for (int d = 0; d < 32; ++d) {
      float qd = (float)qv[d >> 3][d & 7];
#pragma unroll
      for (int n = 0; n < NB; ++n) f[n] += qd * oms[n * 64 + half * 32 + d];
    }
    float sum = 1e-6f;
    float e[NB];
#pragma unroll
    for (int n = 0; n < NB; ++n) {
      float full = f[n] + __shfl_xor(f[n], 1);
      e[n] = __expf(-0.5f * full * full);
      sum += e[n];
    }
    float inv = 1.f / sum;
    if (half == 0) {
      float den = 1e-6f;
      const float* Pr = &Ps[(p >> 2) * CSW];
#pragma unroll
      for (int n = 0; n < NB; ++n) {
        float qn = e[n] * inv;
        qps[p][n] = qn;
        den += qn * Pr[n];
      }
      qps[p][7] = 1.f / den;
    }
  }
  __syncthreads();
  {
    const int d = tid & 63, w = tid >> 6;
    for (int qq = w; qq < 128; qq += 4) {
      const float* Pr = &Ps[(qq >> 2) * CSW + 8 + d];
      float num = 0.f;
#pragma unroll
      for (int n = 0; n < NB; ++n) num += qps[qq][n] * Pr[n * 64];
      attn[((size_t)(b * Sq + s0 + qq)) * Dm + h * 64 + d] = (bf16)(num * qps[qq][7]);
    }
  }
}

// ---------------------------------------------------------------------------
extern "C" void kernel_launch(void* const* d_in, const int* in_sizes, int n_in,
                              void* d_out, int out_size, void* d_ws, size_t ws_size,
                              hipStream_t stream) {
  const float* x    = (const float*)d_in[0];
  const float* lto  = (const float*)d_in[1];
  const float* w_s[4] = {(const float*)d_in[2], (const float*)d_in[3],
                         (const float*)d_in[4], (const float*)d_in[5]};
  const float* w_c[4] = {(const float*)d_in[6], (const float*)d_in[7],
                         (const float*)d_in[8], (const float*)d_in[9]};
  const float* omega_s = (const float*)d_in[10];
  const float* omega_c = (const float*)d_in[11];
  const float* w1 = (const float*)d_in[12];
  const float* b1 = (const float*)d_in[13];
  const float* w2 = (const float*)d_in[14];
  const float* b2 = (const float*)d_in[15];
  const float* ln_a[3] = {(const float*)d_in[16], (const float*)d_in[18], (const float*)d_in[20]};
  const float* ln_b[3] = {(const float*)d_in[17], (const float*)d_in[19], (const float*)d_in[21]};

  char* ws = (char*)d_ws;
  size_t off = 0;
  auto alloc = [&](size_t bytes) -> char* {
    char* p = ws + off;
    off += (bytes + 255) & ~(size_t)255;
    return p;
  };

  const size_t actB = (size_t)Mrows * Dm * sizeof(bf16);   // 16 MiB
  bf16* wb[8];
  for (int i = 0; i < 8; ++i) wb[i] = (bf16*)alloc((size_t)Dm * Dm * 2);
  bf16* w1b = (bf16*)alloc((size_t)Dff * Dm * 2);
  bf16* w2b = (bf16*)alloc((size_t)Dff * Dm * 2);
  bf16* xnb  = (bf16*)alloc(actB);
  bf16* qb   = (bf16*)alloc(actB);   // qb,kb,vb,attnb contiguous -> reused as hb
  bf16* kb   = (bf16*)alloc(actB);
  bf16* vb   = (bf16*)alloc(actB);
  bf16* attnb= (bf16*)alloc(actB);
  bf16* x2b  = (bf16*)alloc(actB);
  bf16* ln1b = (bf16*)alloc(actB);
  float* lto2 = (float*)alloc((size_t)Mrows * Dm * 4);
  float* CSb  = (float*)alloc((size_t)32 * NCH * CSW * 4);
  float* stb  = (float*)alloc((size_t)32 * 8 * CSW * 4);
  bf16* fnb = xnb;        // xnb dead after QKV_s GEMMs
  bf16* hb  = qb;         // qb..attnb (4 x 16MiB = 64MiB) dead after final O GEMM

  const int n4w = Dm * Dm / 4;
  for (int i = 0; i < 4; ++i) cvt_kernel<<<n4w / 256, 256, 0, stream>>>(w_s[i], wb[i], n4w);
  for (int i = 0; i < 4; ++i) cvt_kernel<<<n4w / 256, 256, 0, stream>>>(w_c[i], wb[4 + i], n4w);
  const int n4f = Dff * Dm / 4;
  cvt_kernel<<<n4f / 256, 256, 0, stream>>>(w1, w1b, n4f);
  cvt_kernel<<<n4f / 256, 256, 0, stream>>>(w2, w2b, n4f);

  dim3 g1024(1024 / 128, Mrows / 128);
  dim3 g4096(4096 / 128, Mrows / 128);
  dim3 gperf(Sq / 128, Bq * 16);
  dim3 gscan(8, Bq * 16);

  // --- self performer on x ---
  ln_kernel<<<Mrows, 256, 0, stream>>>(x, ln_a[0], ln_b[0], xnb);
  gemm_bt<0><<<g1024, 256, 0, stream>>>(xnb, wb[0], Mrows, 1024, 1024, nullptr, nullptr, nullptr, qb);
  gemm_bt<0><<<g1024, 256, 0, stream>>>(xnb, wb[1], Mrows, 1024, 1024, nullptr, nullptr, nullptr, kb);
  gemm_bt<0><<<g1024, 256, 0, stream>>>(xnb, wb[2], Mrows, 1024, 1024, nullptr, nullptr, nullptr, vb);
  perf_chunks<<<gperf, 256, 0, stream>>>(kb, vb, omega_s, CSb);
  perf_scan<<<gscan, 256, 0, stream>>>(CSb, stb);
  perf_scan2<<<32, 256, 0, stream>>>(stb);
  perf_out<<<gperf, 256, 0, stream>>>(qb, omega_s, CSb, stb, attnb);
  gemm_bt<1><<<g1024, 256, 0, stream>>>(attnb, wb[3], Mrows, 1024, 1024, nullptr, x, nullptr, x2b);

  // --- cross performer: q from LN(lto), k/v from updated x ---
  ln_kernel<<<Mrows, 256, 0, stream>>>(lto, ln_a[1], ln_b[1], ln1b);
  gemm_bt<0><<<g1024, 256, 0, stream>>>(ln1b, wb[4], Mrows, 1024, 1024, nullptr, nullptr, nullptr, qb);
  gemm_bt<0><<<g1024, 256, 0, stream>>>(x2b,  wb[5], Mrows, 1024, 1024, nullptr, nullptr, nullptr, kb);
  gemm_bt<0><<<g1024, 256, 0, stream>>>(x2b,  wb[6], Mrows, 1024, 1024, nullptr, nullptr, nullptr, vb);
  perf_chunks<<<gperf, 256, 0, stream>>>(kb, vb, omega_c, CSb);
  perf_scan<<<gscan, 256, 0, stream>>>(CSb, stb);
  perf_scan2<<<32, 256, 0, stream>>>(stb);
  perf_out<<<gperf, 256, 0, stream>>>(qb, omega_c, CSb, stb, attnb);
  gemm_bt<2><<<g1024, 256, 0, stream>>>(attnb, wb[7], Mrows, 1024, 1024, nullptr, lto, lto2, nullptr);

  // --- FFN ---
  ln_kernel<<<Mrows, 256, 0, stream>>>(lto2, ln_a[2], ln_b[2], fnb);
  gemm_bt<3><<<g4096, 256, 0, stream>>>(fnb, w1b, Mrows, 4096, 1024, b1, nullptr, nullptr, hb);
  gemm_bt<4><<<g1024, 256, 0, stream>>>(hb, w2b, Mrows, 1024, 4096, b2, lto2, (float*)d_out, nullptr);
}

// Round 2
// 700.905 us; speedup vs baseline: 1.1655x; 1.1655x over previous
//
#include <hip/hip_runtime.h>
#include <cstdint>
#include <cstddef>

typedef __bf16 bf16;
typedef __bf16 bf16x8 __attribute__((ext_vector_type(8)));
typedef __bf16 bf16x4 __attribute__((ext_vector_type(4)));
typedef float  f32x4  __attribute__((ext_vector_type(4)));

#define NB 7
static constexpr int Bq = 2, Sq = 4096, Dm = 1024, Dff = 4096;
static constexpr int Mrows = Bq * Sq;     // 8192
static constexpr int NCH = Sq / 4;        // 1024 chunks per (b,h)
static constexpr int CSW = 464;           // padded prefix-state row width

__device__ __forceinline__ void gload16(const void* g, void* l) {
  __builtin_amdgcn_global_load_lds((__attribute__((address_space(1))) void*)g,
                                   (__attribute__((address_space(3))) void*)l,
                                   16, 0, 0);
}

template <int N> __device__ __forceinline__ void wait_vmcnt() {
  asm volatile("s_waitcnt vmcnt(%0)" :: "n"(N) : "memory");
}
__device__ __forceinline__ void wait_lgkm0() {
  asm volatile("s_waitcnt lgkmcnt(0)" ::: "memory");
}
__device__ __forceinline__ void sbar() {
  __builtin_amdgcn_sched_barrier(0);
  __builtin_amdgcn_s_barrier();
  __builtin_amdgcn_sched_barrier(0);
}

__device__ __forceinline__ float gelu_f(float x) {
  const float c = 0.79788456080286535588f;
  float z = c * (x + 0.044715f * x * x * x);
  float t = 1.f - 2.f / (__expf(2.f * z) + 1.f);   // tanh(z)
  return 0.5f * x * (1.f + t);
}

// ---------------- f32 -> bf16 convert ----------------
__global__ __launch_bounds__(256) void cvt_kernel(const float* __restrict__ in,
                                                  bf16* __restrict__ out, int n4) {
  int i = blockIdx.x * 256 + threadIdx.x;
  if (i >= n4) return;
  f32x4 v = *(const f32x4*)&in[(size_t)i * 4];
  bf16x4 o;
#pragma unroll
  for (int e = 0; e < 4; ++e) o[e] = (bf16)v[e];
  *(bf16x4*)&out[(size_t)i * 4] = o;
}

// ---------------- LayerNorm (ddof=1, /(std+eps)) -> bf16 ----------------
__global__ __launch_bounds__(256) void ln_kernel(const float* __restrict__ x,
                                                 const float* __restrict__ alpha,
                                                 const float* __restrict__ beta,
                                                 bf16* __restrict__ out) {
  const int row = blockIdx.x, tid = threadIdx.x;
  const float* xr = x + (size_t)row * Dm;
  f32x4 v = *(const f32x4*)&xr[tid * 4];
  float s  = v[0] + v[1] + v[2] + v[3];
  float s2 = v[0]*v[0] + v[1]*v[1] + v[2]*v[2] + v[3]*v[3];
#pragma unroll
  for (int o = 32; o > 0; o >>= 1) { s += __shfl_xor(s, o); s2 += __shfl_xor(s2, o); }
  __shared__ float red[8];
  const int wid = tid >> 6, lane = tid & 63;
  if (lane == 0) { red[wid] = s; red[wid + 4] = s2; }
  __syncthreads();
  s  = red[0] + red[1] + red[2] + red[3];
  s2 = red[4] + red[5] + red[6] + red[7];
  const float mean = s * (1.f / 1024.f);
  float var = (s2 - s * mean) * (1.f / 1023.f);
  var = fmaxf(var, 0.f);
  const float inv = 1.f / (sqrtf(var) + 1e-6f);
  f32x4 a4 = *(const f32x4*)&alpha[tid * 4];
  f32x4 b4 = *(const f32x4*)&beta[tid * 4];
  bf16x4 o4;
#pragma unroll
  for (int e = 0; e < 4; ++e) o4[e] = (bf16)(a4[e] * (v[e] - mean) * inv + b4[e]);
  *(bf16x4*)&out[(size_t)row * Dm + tid * 4] = o4;
}

// ---------------- 8-phase double-buffered GEMM: C[M,N] = A @ W^T ----------------
// BM x 256 tile, BK=64, 512 threads (8 waves, 2x4). Staging runs 2 tiles ahead
// into the just-consumed half of the current buffer; boundary vmcnt(LPT) before
// the phase-4 barrier; LDS XOR-swizzle (unit ^= row&7) via pre-swizzled source.
// MODE 0: out bf16 | 1: +res(f32)->bf16 | 2: +res(f32)->f32 | 3: +bias,gelu->bf16
// MODE 4: +bias+res(f32)->f32
template <int BM, int MODE>
__global__ __launch_bounds__(512, 2) void gemm256(
    const bf16* __restrict__ A, const bf16* __restrict__ Bw,
    int M, int N, int K,
    const float* __restrict__ bias, const float* __restrict__ res,
    float* __restrict__ outF, bf16* __restrict__ outB) {
  static_assert(BM == 256 || BM == 128, "BM");
  constexpr int BN  = 256;
  constexpr int ACH = BM / 64;     // 8KB A chunks: 4 or 2
  constexpr int LPT = ACH + 4;     // gloads per tile per wave: 8 or 6
  constexpr int MFR = BM / 32;     // M frags per wave: 8 or 4
  constexpr int MH  = MFR / 2;
  __shared__ __align__(16) bf16 As[2][BM * 64];
  __shared__ __align__(16) bf16 Bs[2][BN * 64];

  const int tid = threadIdx.x;
  const int lane = tid & 63, wid = tid >> 6;
  const int wm = wid >> 2, wn = wid & 3;

  int bid = blockIdx.x;
  const int nwg = gridDim.x;
  bid = (bid & 7) * (nwg >> 3) + (bid >> 3);   // XCD swizzle (nwg % 8 == 0)
  const int nbx = N / BN;
  const int bm = (bid / nbx) * BM, bn = (bid % nbx) * BN;
  const int NT = K >> 6;

  const int srow = tid >> 3;                       // row-in-chunk 0..63
  const int scol = ((tid & 7) ^ (srow & 7)) * 8;   // inverse-swizzled k offset
  const bf16* Ag = A  + (size_t)(bm + srow) * K + scol;
  const bf16* Bg = Bw + (size_t)(bn + srow) * K + scol;

  f32x4 acc[MFR][4] = {};
  const int lr = lane & 15, uo = lane >> 4;

  auto stA = [&](int buf, int t) {
#pragma unroll
    for (int c = 0; c < ACH; ++c)
      gload16(Ag + ((size_t)(c * 64) * K + (size_t)t * 64),
              (char*)(&As[buf][0]) + c * 8192 + wid * 1024);
  };
  auto stB = [&](int buf, int t) {
#pragma unroll
    for (int c = 0; c < 4; ++c)
      gload16(Bg + ((size_t)(c * 64) * K + (size_t)t * 64),
              (char*)(&Bs[buf][0]) + c * 8192 + wid * 1024);
  };

  // prologue: stage tiles 0 and 1
  stA(0, 0); stB(0, 0);
  stA(1, 1); stB(1, 1);
  wait_vmcnt<LPT>();   // tile 0 complete (tile 1's LPT still in flight)
  sbar();

  bf16x8 a0[MH][2], a1[MH][2], b0[2][2], b1[2][2];

  for (int t = 0; t < NT; ++t) {
    const int cur = t & 1;
    const bf16* Asb = &As[cur][0];
    const bf16* Bsb = &Bs[cur][0];

    // ---- P1: read A0 + B0 -> MFMA Q(0,0) ----
#pragma unroll
    for (int i = 0; i < MH; ++i)
#pragma unroll
      for (int kh = 0; kh < 2; ++kh) {
        const int r = wm * (BM / 2) + i * 16 + lr;
        const int u = (kh * 4 + uo) ^ (lr & 7);
        a0[i][kh] = *(const bf16x8*)&Asb[r * 64 + u * 8];
      }
#pragma unroll
    for (int j = 0; j < 2; ++j)
#pragma unroll
      for (int kh = 0; kh < 2; ++kh) {
        const int r = wn * 64 + j * 16 + lr;
        const int u = (kh * 4 + uo) ^ (lr & 7);
        b0[j][kh] = *(const bf16x8*)&Bsb[r * 64 + u * 8];
      }
    __builtin_amdgcn_sched_barrier(0);
    __builtin_amdgcn_s_barrier();
    wait_lgkm0();
    __builtin_amdgcn_sched_barrier(0);
    __builtin_amdgcn_s_setprio(1);
#pragma unroll
    for (int i = 0; i < MH; ++i)
#pragma unroll
      for (int j = 0; j < 2; ++j) {
        acc[i][j] = __builtin_amdgcn_mfma_f32_16x16x32_bf16(a0[i][0], b0[j][0], acc[i][j], 0, 0, 0);
        acc[i][j] = __builtin_amdgcn_mfma_f32_16x16x32_bf16(a0[i][1], b0[j][1], acc[i][j], 0, 0, 0);
      }
    __builtin_amdgcn_s_setprio(0);
    sbar();

    // ---- P2: read B1 -> MFMA Q(0,1) ----
#pragma unroll
    for (int j = 0; j < 2; ++j)
#pragma unroll
      for (int kh = 0; kh < 2; ++kh) {
        const int r = wn * 64 + (2 + j) * 16 + lr;
        const int u = (kh * 4 + uo) ^ (lr & 7);
        b1[j][kh] = *(const bf16x8*)&Bsb[r * 64 + u * 8];
      }
    __builtin_amdgcn_sched_barrier(0);
    __builtin_amdgcn_s_barrier();
    wait_lgkm0();
    __builtin_amdgcn_sched_barrier(0);
    __builtin_amdgcn_s_setprio(1);
#pragma unroll
    for (int i = 0; i < MH; ++i)
#pragma unroll
      for (int j = 0; j < 2; ++j) {
        acc[i][2 + j] = __builtin_amdgcn_mfma_f32_16x16x32_bf16(a0[i][0], b1[j][0], acc[i][2 + j], 0, 0, 0);
        acc[i][2 + j] = __builtin_amdgcn_mfma_f32_16x16x32_bf16(a0[i][1], b1[j][1], acc[i][2 + j], 0, 0, 0);
      }
    __builtin_amdgcn_s_setprio(0);
    sbar();

    // ---- P3: read A1, stage B(t+2) into freed B region -> MFMA Q(1,1) ----
#pragma unroll
    for (int i = 0; i < MH; ++i)
#pragma unroll
      for (int kh = 0; kh < 2; ++kh) {
        const int r = wm * (BM / 2) + (MH + i) * 16 + lr;
        const int u = (kh * 4 + uo) ^ (lr & 7);
        a1[i][kh] = *(const bf16x8*)&Asb[r * 64 + u * 8];
      }
    __builtin_amdgcn_sched_barrier(0);
    if (t + 2 < NT) stB(cur, t + 2);
    __builtin_amdgcn_sched_barrier(0);
    __builtin_amdgcn_s_barrier();
    wait_lgkm0();
    __builtin_amdgcn_sched_barrier(0);
    __builtin_amdgcn_s_setprio(1);
#pragma unroll
    for (int i = 0; i < MH; ++i)
#pragma unroll
      for (int j = 0; j < 2; ++j) {
        acc[MH + i][2 + j] = __builtin_amdgcn_mfma_f32_16x16x32_bf16(a1[i][0], b1[j][0], acc[MH + i][2 + j], 0, 0, 0);
        acc[MH + i][2 + j] = __builtin_amdgcn_mfma_f32_16x16x32_bf16(a1[i][1], b1[j][1], acc[MH + i][2 + j], 0, 0, 0);
      }
    __builtin_amdgcn_s_setprio(0);
    sbar();

    // ---- P4: stage A(t+2) into freed A region -> MFMA Q(1,0), boundary vmcnt ----
    if (t + 2 < NT) stA(cur, t + 2);
    __builtin_amdgcn_sched_barrier(0);
    __builtin_amdgcn_s_barrier();
    __builtin_amdgcn_sched_barrier(0);
    __builtin_amdgcn_s_setprio(1);
#pragma unroll
    for (int i = 0; i < MH; ++i)
#pragma unroll
      for (int j = 0; j < 2; ++j) {
        acc[MH + i][j] = __builtin_amdgcn_mfma_f32_16x16x32_bf16(a1[i][0], b0[j][0], acc[MH + i][j], 0, 0, 0);
        acc[MH + i][j] = __builtin_amdgcn_mfma_f32_16x16x32_bf16(a1[i][1], b0[j][1], acc[MH + i][j], 0, 0, 0);
      }
    __builtin_amdgcn_s_setprio(0);
    __builtin_amdgcn_sched_barrier(0);
    if (t < NT - 2) wait_vmcnt<LPT>();   // next tile fully staged; 1 tile in flight
    else            wait_vmcnt<0>();     // single drain before the final tile
    __builtin_amdgcn_s_barrier();
    __builtin_amdgcn_sched_barrier(0);
  }

  // ---- epilogue ----
#pragma unroll
  for (int f = 0; f < MFR; ++f) {
    const int r0 = bm + wm * (BM / 2) + f * 16 + (lane >> 4) * 4;
#pragma unroll
    for (int g = 0; g < 4; ++g) {
      const int c = bn + wn * 64 + g * 16 + (lane & 15);
      float bv = 0.f;
      if (MODE == 3 || MODE == 4) bv = bias[c];
#pragma unroll
      for (int r = 0; r < 4; ++r) {
        const size_t idx = (size_t)(r0 + r) * N + c;
        float v = acc[f][g][r];
        if (MODE == 1 || MODE == 2) v += res[idx];
        if (MODE == 3) v = gelu_f(v + bv);
        if (MODE == 4) v += bv + res[idx];
        if (MODE == 0 || MODE == 1 || MODE == 3) outB[idx] = (bf16)v;
        else outF[idx] = v;
      }
    }
  }
}

// ---------------- Performer: per-chunk sums of kp and kp (x) v ----------------
__global__ __launch_bounds__(256) void perf_chunks(
    const bf16* __restrict__ kmat, const bf16* __restrict__ vmat, int ld,
    const float* __restrict__ omega, float* __restrict__ CS) {
  const int tid = threadIdx.x;
  const int bh = blockIdx.y, b = bh >> 4, h = bh & 15;
  const int s0 = blockIdx.x * 128;
  __shared__ __align__(16) bf16 vs[128][72];
  __shared__ float kps[128][8];
  __shared__ float oms[NB * 64];

  {
    const bf16* vb = vmat + ((size_t)(b * Sq + s0)) * ld + h * 64;
#pragma unroll
    for (int p = 0; p < 4; ++p) {
      int row = p * 32 + (tid >> 3), c16 = (tid & 7) * 8;
      *(uint4*)&vs[row][c16] = *(const uint4*)&vb[(size_t)row * ld + c16];
    }
  }
  if (tid < 224) { oms[tid] = omega[tid]; oms[tid + 224] = omega[tid + 224]; }
  __syncthreads();
  {
    const int p = tid >> 1, half = tid & 1;
    const bf16* kr = kmat + ((size_t)(b * Sq + s0 + p)) * ld + h * 64 + half * 32;
    bf16x8 kv[4];
#pragma unroll
    for (int q = 0; q < 4; ++q) kv[q] = *(const bf16x8*)&kr[q * 8];
    float f[NB];
#pragma unroll
    for (int n = 0; n < NB; ++n) f[n] = 0.f;
#pragma unroll
    for (int d = 0; d < 32; ++d) {
      float kd = (float)kv[d >> 3][d & 7];
#pragma unroll
      for (int n = 0; n < NB; ++n) f[n] += kd * oms[n * 64 + half * 32 + d];
    }
    float sum = 1e-6f;
    float e[NB];
#pragma unroll
    for (int n = 0; n < NB; ++n) {
      float full = f[n] + __shfl_xor(f[n], 1);
      e[n] = __expf(-0.5f * full * full);
      sum += e[n];
    }
    float inv = 1.f / sum;
    if (half == 0) {
#pragma unroll
      for (int n = 0; n < NB; ++n) kps[p][n] = e[n] * inv;
    }
  }
  __syncthreads();
  {
    const int d = tid & 63, w = tid >> 6;
    float* base = CS + ((size_t)bh * NCH + (s0 >> 2)) * CSW;
    for (int cl = w; cl < 32; cl += 4) {
      float vv[4];
#pragma unroll
      for (int i = 0; i < 4; ++i) vv[i] = (float)vs[cl * 4 + i][d];
#pragma unroll
      for (int n = 0; n < NB; ++n) {
        float a = kps[cl*4+0][n]*vv[0] + kps[cl*4+1][n]*vv[1] +
                  kps[cl*4+2][n]*vv[2] + kps[cl*4+3][n]*vv[3];
        base[(size_t)cl * CSW + 8 + n * 64 + d] = a;
      }
    }
    if (tid < 32) {
#pragma unroll
      for (int n = 0; n < NB; ++n)
        base[(size_t)tid * CSW + n] =
            kps[tid*4][n] + kps[tid*4+1][n] + kps[tid*4+2][n] + kps[tid*4+3][n];
      base[(size_t)tid * CSW + 7] = 0.f;
#pragma unroll
      for (int z = 456; z < 464; ++z) base[(size_t)tid * CSW + z] = 0.f;
    }
  }
}

// ---------------- segment-local inclusive scan (128 chunks) ----------------
__global__ __launch_bounds__(256) void perf_scan(float* __restrict__ CS, float* __restrict__ segtot) {
  const int bh = blockIdx.y, seg = blockIdx.x;
  float* base = CS + ((size_t)bh * NCH + seg * 128) * CSW;
  const int c0 = threadIdx.x;
  float r0 = 0.f, r1 = 0.f;
#pragma unroll 4
  for (int c = 0; c < 128; ++c) {
    float* row = base + (size_t)c * CSW;
    r0 += row[c0]; row[c0] = r0;
    if (c0 + 256 < CSW) { r1 += row[c0 + 256]; row[c0 + 256] = r1; }
  }
  float* st = segtot + ((size_t)bh * 8 + seg) * CSW;
  st[c0] = r0;
  if (c0 + 256 < CSW) st[c0 + 256] = r1;
}

// ---------------- exclusive scan of the 8 segment totals ----------------
__global__ __launch_bounds__(256) void perf_scan2(float* __restrict__ segtot) {
  const int bh = blockIdx.x;
  const int c0 = threadIdx.x;
  float run0 = 0.f, run1 = 0.f;
#pragma unroll
  for (int s = 0; s < 8; ++s) {
    float* st = segtot + ((size_t)bh * 8 + s) * CSW;
    float t0 = st[c0]; st[c0] = run0; run0 += t0;
    if (c0 + 256 < CSW) { float t1 = st[c0 + 256]; st[c0 + 256] = run1; run1 += t1; }
  }
}

// ---------------- Performer output ----------------
__global__ __launch_bounds__(256) void perf_out(
    const bf16* __restrict__ qmat, int ldq, const float* __restrict__ omega,
    const float* __restrict__ CS, const float* __restrict__ segtot,
    bf16* __restrict__ attn) {
  const int tid = threadIdx.x;
  const int bh = blockIdx.y, b = bh >> 4, h = bh & 15;
  const int s0 = blockIdx.x * 128;
  const int cg0 = s0 >> 2;
  const int seg = cg0 >> 7;
  __shared__ __align__(16) float Ps[32 * CSW];
  __shared__ float qps[128][8];
  __shared__ float oms[NB * 64];

  {
    const float* src = CS + ((size_t)bh * NCH + cg0) * CSW;
    const float* off = segtot + ((size_t)bh * 8 + seg) * CSW;
    for (int i = tid; i < 32 * CSW / 4; i += 256) {
      f32x4 a = *(const f32x4*)&src[i * 4];
      f32x4 o = *(const f32x4*)&off[(i % (CSW / 4)) * 4];
      a += o;
      *(f32x4*)&Ps[i * 4] = a;
    }
  }
  if (tid < 224) { oms[tid] = omega[tid]; oms[tid + 224] = omega[tid + 224]; }
  __syncthreads();
  {
    const int p = tid >> 1, half = tid & 1;
    const bf16* qr = qmat + ((size_t)(b * Sq + s0 + p)) * ldq + h * 64 + half * 32;
    bf16x8 qv[4];
#pragma unroll
    for (int q = 0; q < 4; ++q) qv[q] = *(const bf16x8*)&qr[q * 8];
    float f[NB];
#pragma unroll
    for (int n = 0; n < NB; ++n) f[n] = 0.f;
#pragma unroll
    for (int d = 0; d < 32; ++d) {
      float qd = (float)qv[d >> 3][d & 7];
#pragma unroll
      for (int n = 0; n < NB; ++n) f[n] += qd * oms[n * 64 + half * 32 + d];
    }
    float sum = 1e-6f;
    float e[NB];
#pragma unroll
    for (int n = 0; n < NB; ++n) {
      float full = f[n] + __shfl_xor(f[n], 1);
      e[n] = __expf(-0.5f * full * full);
      sum += e[n];
    }
    float inv = 1.f / sum;
    if (half == 0) {
      float den = 1e-6f;
      const float* Pr = &Ps[(p >> 2) * CSW];
#pragma unroll
      for (int n = 0; n < NB; ++n) {
        float qn = e[n] * inv;
        qps[p][n] = qn;
        den += qn * Pr[n];
      }
      qps[p][7] = 1.f / den;
    }
  }
  __syncthreads();
  {
    const int d = tid & 63, w = tid >> 6;
    for (int qq = w; qq < 128; qq += 4) {
      const float* Pr = &Ps[(qq >> 2) * CSW + 8 + d];
      float num = 0.f;
#pragma unroll
      for (int n = 0; n < NB; ++n) num += qps[qq][n] * Pr[n * 64];
      attn[((size_t)(b * Sq + s0 + qq)) * Dm + h * 64 + d] = (bf16)(num * qps[qq][7]);
    }
  }
}

// ---------------------------------------------------------------------------
extern "C" void kernel_launch(void* const* d_in, const int* in_sizes, int n_in,
                              void* d_out, int out_size, void* d_ws, size_t ws_size,
                              hipStream_t stream) {
  const float* x    = (const float*)d_in[0];
  const float* lto  = (const float*)d_in[1];
  const float* w_s[4] = {(const float*)d_in[2], (const float*)d_in[3],
                         (const float*)d_in[4], (const float*)d_in[5]};
  const float* w_c[4] = {(const float*)d_in[6], (const float*)d_in[7],
                         (const float*)d_in[8], (const float*)d_in[9]};
  const float* omega_s = (const float*)d_in[10];
  const float* omega_c = (const float*)d_in[11];
  const float* w1 = (const float*)d_in[12];
  const float* b1 = (const float*)d_in[13];
  const float* w2 = (const float*)d_in[14];
  const float* b2 = (const float*)d_in[15];
  const float* ln_a[3] = {(const float*)d_in[16], (const float*)d_in[18], (const float*)d_in[20]};
  const float* ln_b[3] = {(const float*)d_in[17], (const float*)d_in[19], (const float*)d_in[21]};

  char* ws = (char*)d_ws;
  size_t off = 0;
  auto alloc = [&](size_t bytes) -> char* {
    char* p = ws + off;
    off += (bytes + 255) & ~(size_t)255;
    return p;
  };

  const size_t actB = (size_t)Mrows * Dm * sizeof(bf16);     // 16 MiB
  const size_t MB32 = (size_t)Mrows * 2048 * sizeof(bf16);   // 32 MiB

  bf16* wqkv = (bf16*)alloc((size_t)3072 * 1024 * 2);
  bf16* wo_sb = (bf16*)alloc((size_t)1024 * 1024 * 2);
  bf16* wq_cb = (bf16*)alloc((size_t)1024 * 1024 * 2);
  bf16* wkv  = (bf16*)alloc((size_t)2048 * 1024 * 2);
  bf16* wo_cb = (bf16*)alloc((size_t)1024 * 1024 * 2);
  bf16* w1b = (bf16*)alloc((size_t)Dff * Dm * 2);
  bf16* w2b = (bf16*)alloc((size_t)Dff * Dm * 2);
  bf16* xnb  = (bf16*)alloc(actB);
  char* pool = alloc((size_t)Mrows * Dff * 2);               // 64 MiB shared pool
  bf16* qkvb = (bf16*)pool;                                  // 48 MiB (phase 1)
  bf16* kvb  = (bf16*)pool;                                  // 32 MiB (phase 2)
  bf16* qb   = (bf16*)(pool + MB32);                         // 16 MiB (phase 2)
  bf16* hb   = (bf16*)pool;                                  // 64 MiB (phase 3)
  bf16* attnb= (bf16*)alloc(actB);
  bf16* x2b  = (bf16*)alloc(actB);
  bf16* ln1b = (bf16*)alloc(actB);
  float* lto2 = (float*)alloc((size_t)Mrows * Dm * 4);
  float* CSb  = (float*)alloc((size_t)32 * NCH * CSW * 4);
  float* stb  = (float*)alloc((size_t)32 * 8 * CSW * 4);
  bf16* fnb = xnb;   // xnb dead after QKV_s GEMM

  const int n4w = Dm * Dm / 4;
  cvt_kernel<<<n4w / 256, 256, 0, stream>>>(w_s[0], wqkv, n4w);
  cvt_kernel<<<n4w / 256, 256, 0, stream>>>(w_s[1], wqkv + 1024 * 1024, n4w);
  cvt_kernel<<<n4w / 256, 256, 0, stream>>>(w_s[2], wqkv + 2 * 1024 * 1024, n4w);
  cvt_kernel<<<n4w / 256, 256, 0, stream>>>(w_s[3], wo_sb, n4w);
  cvt_kernel<<<n4w / 256, 256, 0, stream>>>(w_c[0], wq_cb, n4w);
  cvt_kernel<<<n4w / 256, 256, 0, stream>>>(w_c[1], wkv, n4w);
  cvt_kernel<<<n4w / 256, 256, 0, stream>>>(w_c[2], wkv + 1024 * 1024, n4w);
  cvt_kernel<<<n4w / 256, 256, 0, stream>>>(w_c[3], wo_cb, n4w);
  const int n4f = Dff * Dm / 4;
  cvt_kernel<<<n4f / 256, 256, 0, stream>>>(w1, w1b, n4f);
  cvt_kernel<<<n4f / 256, 256, 0, stream>>>(w2, w2b, n4f);

  dim3 gperf(Sq / 128, Bq * 16);
  dim3 gscan(8, Bq * 16);
  const int gQKV = (Mrows / 256) * (3072 / 256);   // 384
  const int gKV  = (Mrows / 256) * (2048 / 256);   // 256
  const int gFF1 = (Mrows / 256) * (4096 / 256);   // 512
  const int gN1k = (Mrows / 128) * (1024 / 256);   // 256

  // --- self performer on x ---
  ln_kernel<<<Mrows, 256, 0, stream>>>(x, ln_a[0], ln_b[0], xnb);
  gemm256<256, 0><<<gQKV, 512, 0, stream>>>(xnb, wqkv, Mrows, 3072, 1024, nullptr, nullptr, nullptr, qkvb);
  perf_chunks<<<gperf, 256, 0, stream>>>(qkvb + 1024, qkvb + 2048, 3072, omega_s, CSb);
  perf_scan<<<gscan, 256, 0, stream>>>(CSb, stb);
  perf_scan2<<<32, 256, 0, stream>>>(stb);
  perf_out<<<gperf, 256, 0, stream>>>(qkvb, 3072, omega_s, CSb, stb, attnb);
  gemm256<128, 1><<<gN1k, 512, 0, stream>>>(attnb, wo_sb, Mrows, 1024, 1024, nullptr, x, nullptr, x2b);

  // --- cross performer: q from LN(lto), k/v from updated x ---
  ln_kernel<<<Mrows, 256, 0, stream>>>(lto, ln_a[1], ln_b[1], ln1b);
  gemm256<128, 0><<<gN1k, 512, 0, stream>>>(ln1b, wq_cb, Mrows, 1024, 1024, nullptr, nullptr, nullptr, qb);
  gemm256<256, 0><<<gKV, 512, 0, stream>>>(x2b, wkv, Mrows, 2048, 1024, nullptr, nullptr, nullptr, kvb);
  perf_chunks<<<gperf, 256, 0, stream>>>(kvb, kvb + 1024, 2048, omega_c, CSb);
  perf_scan<<<gscan, 256, 0, stream>>>(CSb, stb);
  perf_scan2<<<32, 256, 0, stream>>>(stb);
  perf_out<<<gperf, 256, 0, stream>>>(qb, 1024, omega_c, CSb, stb, attnb);
  gemm256<128, 2><<<gN1k, 512, 0, stream>>>(attnb, wo_cb, Mrows, 1024, 1024, nullptr, lto, lto2, nullptr);

  // --- FFN ---
  ln_kernel<<<Mrows, 256, 0, stream>>>(lto2, ln_a[2], ln_b[2], fnb);
  gemm256<256, 3><<<gFF1, 512, 0, stream>>>(fnb, w1b, Mrows, 4096, 1024, b1, nullptr, nullptr, hb);
  gemm256<128, 4><<<gN1k, 512, 0, stream>>>(hb, w2b, Mrows, 1024, 4096, b2, lto2, (float*)d_out, nullptr);
}

// Round 3
// 596.831 us; speedup vs baseline: 1.3688x; 1.1744x over previous
//
#include <hip/hip_runtime.h>
#include <cstdint>
#include <cstddef>

typedef __bf16 bf16;
typedef __bf16 bf16x8 __attribute__((ext_vector_type(8)));
typedef __bf16 bf16x4 __attribute__((ext_vector_type(4)));
typedef float  f32x4  __attribute__((ext_vector_type(4)));

#define NB 7
static constexpr int Bq = 2, Sq = 4096, Dm = 1024, Dff = 4096;
static constexpr int Mrows = Bq * Sq;     // 8192
static constexpr int NCH = Sq / 4;        // 1024 chunks per (b,h)
static constexpr int CSW = 464;           // padded prefix-state row width

__device__ __forceinline__ void gload16(const void* g, void* l) {
  __builtin_amdgcn_global_load_lds((__attribute__((address_space(1))) void*)g,
                                   (__attribute__((address_space(3))) void*)l,
                                   16, 0, 0);
}

template <int N> __device__ __forceinline__ void wait_vmcnt() {
  asm volatile("s_waitcnt vmcnt(%0)" :: "n"(N) : "memory");
}
__device__ __forceinline__ void wait_lgkm0() {
  asm volatile("s_waitcnt lgkmcnt(0)" ::: "memory");
}
__device__ __forceinline__ void sbar() {
  __builtin_amdgcn_sched_barrier(0);
  __builtin_amdgcn_s_barrier();
  __builtin_amdgcn_sched_barrier(0);
}

__device__ __forceinline__ float gelu_f(float x) {
  const float c = 0.79788456080286535588f;
  float z = c * (x + 0.044715f * x * x * x);
  float t = 1.f - 2.f / (__expf(2.f * z) + 1.f);   // tanh(z)
  return 0.5f * x * (1.f + t);
}

// ---------------- batched f32 -> bf16 convert (10 regions, 1 launch) ----------
struct CvtA {
  const float* s[10];
  bf16* d[10];
  int start[11];   // region boundaries in n4 units (multiples of 256)
};
__global__ __launch_bounds__(256) void cvt10(CvtA a) {
  const int i = blockIdx.x * 256 + threadIdx.x;
  int r = 0;
#pragma unroll
  for (int k = 1; k < 10; ++k) r += (i >= a.start[k]);
  const int o = i - a.start[r];
  f32x4 v = *(const f32x4*)&a.s[r][(size_t)o * 4];
  bf16x4 ov;
#pragma unroll
  for (int e = 0; e < 4; ++e) ov[e] = (bf16)v[e];
  *(bf16x4*)&a.d[r][(size_t)o * 4] = ov;
}

// ---------------- LayerNorm (ddof=1, /(std+eps)) -> bf16 ----------------
__global__ __launch_bounds__(256) void ln_kernel(const float* __restrict__ x,
                                                 const float* __restrict__ alpha,
                                                 const float* __restrict__ beta,
                                                 bf16* __restrict__ out) {
  const int row = blockIdx.x, tid = threadIdx.x;
  const float* xr = x + (size_t)row * Dm;
  f32x4 v = *(const f32x4*)&xr[tid * 4];
  float s  = v[0] + v[1] + v[2] + v[3];
  float s2 = v[0]*v[0] + v[1]*v[1] + v[2]*v[2] + v[3]*v[3];
#pragma unroll
  for (int o = 32; o > 0; o >>= 1) { s += __shfl_xor(s, o); s2 += __shfl_xor(s2, o); }
  __shared__ float red[8];
  const int wid = tid >> 6, lane = tid & 63;
  if (lane == 0) { red[wid] = s; red[wid + 4] = s2; }
  __syncthreads();
  s  = red[0] + red[1] + red[2] + red[3];
  s2 = red[4] + red[5] + red[6] + red[7];
  const float mean = s * (1.f / 1024.f);
  float var = (s2 - s * mean) * (1.f / 1023.f);
  var = fmaxf(var, 0.f);
  const float inv = 1.f / (sqrtf(var) + 1e-6f);
  f32x4 a4 = *(const f32x4*)&alpha[tid * 4];
  f32x4 b4 = *(const f32x4*)&beta[tid * 4];
  bf16x4 o4;
#pragma unroll
  for (int e = 0; e < 4; ++e) o4[e] = (bf16)(a4[e] * (v[e] - mean) * inv + b4[e]);
  *(bf16x4*)&out[(size_t)row * Dm + tid * 4] = o4;
}

// ---------------- 8-phase double-buffered GEMM, BM=256 x BN=256 ----------------
// MODE 0: out bf16 | 3: +bias,gelu->bf16
template <int MODE>
__global__ __launch_bounds__(512, 2) void gemm256(
    const bf16* __restrict__ A, const bf16* __restrict__ Bw,
    int M, int N, int K,
    const float* __restrict__ bias, const float* __restrict__ res,
    float* __restrict__ outF, bf16* __restrict__ outB) {
  constexpr int BM = 256, BN = 256;
  constexpr int ACH = 4, LPT = 8, MFR = 8, MH = 4;
  __shared__ __align__(16) bf16 As[2][BM * 64];
  __shared__ __align__(16) bf16 Bs[2][BN * 64];

  const int tid = threadIdx.x;
  const int lane = tid & 63, wid = tid >> 6;
  const int wm = wid >> 2, wn = wid & 3;

  int bid = blockIdx.x;
  const int nwg = gridDim.x;
  bid = (bid & 7) * (nwg >> 3) + (bid >> 3);   // XCD swizzle (nwg % 8 == 0)
  const int nbx = N / BN;
  const int bm = (bid / nbx) * BM, bn = (bid % nbx) * BN;
  const int NT = K >> 6;

  const int srow = tid >> 3;
  const int scol = ((tid & 7) ^ (srow & 7)) * 8;
  const bf16* Ag = A  + (size_t)(bm + srow) * K + scol;
  const bf16* Bg = Bw + (size_t)(bn + srow) * K + scol;

  f32x4 acc[MFR][4] = {};
  const int lr = lane & 15, uo = lane >> 4;

  auto stA = [&](int buf, int t) {
#pragma unroll
    for (int c = 0; c < ACH; ++c)
      gload16(Ag + ((size_t)(c * 64) * K + (size_t)t * 64),
              (char*)(&As[buf][0]) + c * 8192 + wid * 1024);
  };
  auto stB = [&](int buf, int t) {
#pragma unroll
    for (int c = 0; c < 4; ++c)
      gload16(Bg + ((size_t)(c * 64) * K + (size_t)t * 64),
              (char*)(&Bs[buf][0]) + c * 8192 + wid * 1024);
  };

  stA(0, 0); stB(0, 0);
  stA(1, 1); stB(1, 1);
  wait_vmcnt<LPT>();
  sbar();

  bf16x8 a0[MH][2], a1[MH][2], b0[2][2], b1[2][2];

  for (int t = 0; t < NT; ++t) {
    const int cur = t & 1;
    const bf16* Asb = &As[cur][0];
    const bf16* Bsb = &Bs[cur][0];

    // ---- P1: read A0 + B0 -> MFMA Q(0,0) ----
#pragma unroll
    for (int i = 0; i < MH; ++i)
#pragma unroll
      for (int kh = 0; kh < 2; ++kh) {
        const int r = wm * (BM / 2) + i * 16 + lr;
        const int u = (kh * 4 + uo) ^ (lr & 7);
        a0[i][kh] = *(const bf16x8*)&Asb[r * 64 + u * 8];
      }
#pragma unroll
    for (int j = 0; j < 2; ++j)
#pragma unroll
      for (int kh = 0; kh < 2; ++kh) {
        const int r = wn * 64 + j * 16 + lr;
        const int u = (kh * 4 + uo) ^ (lr & 7);
        b0[j][kh] = *(const bf16x8*)&Bsb[r * 64 + u * 8];
      }
    __builtin_amdgcn_sched_barrier(0);
    __builtin_amdgcn_s_barrier();
    wait_lgkm0();
    __builtin_amdgcn_sched_barrier(0);
    __builtin_amdgcn_s_setprio(1);
#pragma unroll
    for (int i = 0; i < MH; ++i)
#pragma unroll
      for (int j = 0; j < 2; ++j) {
        acc[i][j] = __builtin_amdgcn_mfma_f32_16x16x32_bf16(a0[i][0], b0[j][0], acc[i][j], 0, 0, 0);
        acc[i][j] = __builtin_amdgcn_mfma_f32_16x16x32_bf16(a0[i][1], b0[j][1], acc[i][j], 0, 0, 0);
      }
    __builtin_amdgcn_s_setprio(0);
    sbar();

    // ---- P2: read B1 -> MFMA Q(0,1) ----
#pragma unroll
    for (int j = 0; j < 2; ++j)
#pragma unroll
      for (int kh = 0; kh < 2; ++kh) {
        const int r = wn * 64 + (2 + j) * 16 + lr;
        const int u = (kh * 4 + uo) ^ (lr & 7);
        b1[j][kh] = *(const bf16x8*)&Bsb[r * 64 + u * 8];
      }
    __builtin_amdgcn_sched_barrier(0);
    __builtin_amdgcn_s_barrier();
    wait_lgkm0();
    __builtin_amdgcn_sched_barrier(0);
    __builtin_amdgcn_s_setprio(1);
#pragma unroll
    for (int i = 0; i < MH; ++i)
#pragma unroll
      for (int j = 0; j < 2; ++j) {
        acc[i][2 + j] = __builtin_amdgcn_mfma_f32_16x16x32_bf16(a0[i][0], b1[j][0], acc[i][2 + j], 0, 0, 0);
        acc[i][2 + j] = __builtin_amdgcn_mfma_f32_16x16x32_bf16(a0[i][1], b1[j][1], acc[i][2 + j], 0, 0, 0);
      }
    __builtin_amdgcn_s_setprio(0);
    sbar();

    // ---- P3: read A1, stage B(t+2) -> MFMA Q(1,1) ----
#pragma unroll
    for (int i = 0; i < MH; ++i)
#pragma unroll
      for (int kh = 0; kh < 2; ++kh) {
        const int r = wm * (BM / 2) + (MH + i) * 16 + lr;
        const int u = (kh * 4 + uo) ^ (lr & 7);
        a1[i][kh] = *(const bf16x8*)&Asb[r * 64 + u * 8];
      }
    __builtin_amdgcn_sched_barrier(0);
    if (t + 2 < NT) stB(cur, t + 2);
    __builtin_amdgcn_sched_barrier(0);
    __builtin_amdgcn_s_barrier();
    wait_lgkm0();
    __builtin_amdgcn_sched_barrier(0);
    __builtin_amdgcn_s_setprio(1);
#pragma unroll
    for (int i = 0; i < MH; ++i)
#pragma unroll
      for (int j = 0; j < 2; ++j) {
        acc[MH + i][2 + j] = __builtin_amdgcn_mfma_f32_16x16x32_bf16(a1[i][0], b1[j][0], acc[MH + i][2 + j], 0, 0, 0);
        acc[MH + i][2 + j] = __builtin_amdgcn_mfma_f32_16x16x32_bf16(a1[i][1], b1[j][1], acc[MH + i][2 + j], 0, 0, 0);
      }
    __builtin_amdgcn_s_setprio(0);
    sbar();

    // ---- P4: stage A(t+2) -> MFMA Q(1,0), boundary vmcnt ----
    if (t + 2 < NT) stA(cur, t + 2);
    __builtin_amdgcn_sched_barrier(0);
    __builtin_amdgcn_s_barrier();
    __builtin_amdgcn_sched_barrier(0);
    __builtin_amdgcn_s_setprio(1);
#pragma unroll
    for (int i = 0; i < MH; ++i)
#pragma unroll
      for (int j = 0; j < 2; ++j) {
        acc[MH + i][j] = __builtin_amdgcn_mfma_f32_16x16x32_bf16(a1[i][0], b0[j][0], acc[MH + i][j], 0, 0, 0);
        acc[MH + i][j] = __builtin_amdgcn_mfma_f32_16x16x32_bf16(a1[i][1], b0[j][1], acc[MH + i][j], 0, 0, 0);
      }
    __builtin_amdgcn_s_setprio(0);
    __builtin_amdgcn_sched_barrier(0);
    if (t < NT - 2) wait_vmcnt<LPT>();
    else            wait_vmcnt<0>();
    __builtin_amdgcn_s_barrier();
    __builtin_amdgcn_sched_barrier(0);
  }

#pragma unroll
  for (int f = 0; f < MFR; ++f) {
    const int r0 = bm + wm * (BM / 2) + f * 16 + (lane >> 4) * 4;
#pragma unroll
    for (int g = 0; g < 4; ++g) {
      const int c = bn + wn * 64 + g * 16 + (lane & 15);
      float bv = 0.f;
      if (MODE == 3) bv = bias[c];
#pragma unroll
      for (int r = 0; r < 4; ++r) {
        const size_t idx = (size_t)(r0 + r) * N + c;
        float v = acc[f][g][r];
        if (MODE == 3) v = gelu_f(v + bv);
        outB[idx] = (bf16)v;
      }
    }
  }
}

// ---------------- 2-phase triple-buffered GEMM, BM=128 x BN=256 ----------------
// 16 MFMA per phase; staging t+2 into buf[(t+2)%3] is race-free (that buffer was
// last read in tile t-1, drained before its final barrier).
// MODE 0: out bf16 | 1: +res(f32)->bf16 | 2: +res(f32)->f32 | 4: +bias+res->f32
template <int MODE>
__global__ __launch_bounds__(512, 2) void gemm128(
    const bf16* __restrict__ A, const bf16* __restrict__ Bw,
    int M, int N, int K,
    const float* __restrict__ bias, const float* __restrict__ res,
    float* __restrict__ outF, bf16* __restrict__ outB) {
  constexpr int BM = 128, BN = 256;
  __shared__ __align__(16) bf16 As[3][BM * 64];   // 48 KB
  __shared__ __align__(16) bf16 Bs[3][BN * 64];   // 96 KB

  const int tid = threadIdx.x;
  const int lane = tid & 63, wid = tid >> 6;
  const int wm = wid >> 2, wn = wid & 3;

  int bid = blockIdx.x;
  const int nwg = gridDim.x;
  bid = (bid & 7) * (nwg >> 3) + (bid >> 3);
  const int nbx = N / BN;
  const int bm = (bid / nbx) * BM, bn = (bid % nbx) * BN;
  const int NT = K >> 6;

  const int srow = tid >> 3;
  const int scol = ((tid & 7) ^ (srow & 7)) * 8;
  const bf16* Ag = A  + (size_t)(bm + srow) * K + scol;
  const bf16* Bg = Bw + (size_t)(bn + srow) * K + scol;

  f32x4 acc[4][4] = {};
  const int lr = lane & 15, uo = lane >> 4;

  auto stA = [&](int buf, int t) {
#pragma unroll
    for (int c = 0; c < 2; ++c)
      gload16(Ag + ((size_t)(c * 64) * K + (size_t)t * 64),
              (char*)(&As[buf][0]) + c * 8192 + wid * 1024);
  };
  auto stB = [&](int buf, int t) {
#pragma unroll
    for (int c = 0; c < 4; ++c)
      gload16(Bg + ((size_t)(c * 64) * K + (size_t)t * 64),
              (char*)(&Bs[buf][0]) + c * 8192 + wid * 1024);
  };

  stA(0, 0); stB(0, 0);
  stA(1, 1); stB(1, 1);
  wait_vmcnt<6>();
  sbar();

  bf16x8 a0[2][2], a1[2][2], bv[4][2];
  int cur = 0;
  for (int t = 0; t < NT; ++t) {
    const bf16* Asb = &As[cur][0];
    const bf16* Bsb = &Bs[cur][0];
    const int nxt2 = (cur == 0) ? 2 : cur - 1;   // (t+2) % 3

    // ---- Phase A: read a0 + all B, stage tile t+2 -> MFMA rows 0..63 ----
#pragma unroll
    for (int i = 0; i < 2; ++i)
#pragma unroll
      for (int kh = 0; kh < 2; ++kh) {
        const int r = wm * 64 + i * 16 + lr;
        const int u = (kh * 4 + uo) ^ (lr & 7);
        a0[i][kh] = *(const bf16x8*)&Asb[r * 64 + u * 8];
      }
#pragma unroll
    for (int j = 0; j < 4; ++j)
#pragma unroll
      for (int kh = 0; kh < 2; ++kh) {
        const int r = wn * 64 + j * 16 + lr;
        const int u = (kh * 4 + uo) ^ (lr & 7);
        bv[j][kh] = *(const bf16x8*)&Bsb[r * 64 + u * 8];
      }
    __builtin_amdgcn_sched_barrier(0);
    if (t + 2 < NT) { stB(nxt2, t + 2); stA(nxt2, t + 2); }
    __builtin_amdgcn_sched_barrier(0);
    __builtin_amdgcn_s_barrier();
    wait_lgkm0();
    __builtin_amdgcn_sched_barrier(0);
    __builtin_amdgcn_s_setprio(1);
#pragma unroll
    for (int i = 0; i < 2; ++i)
#pragma unroll
      for (int j = 0; j < 4; ++j) {
        acc[i][j] = __builtin_amdgcn_mfma_f32_16x16x32_bf16(a0[i][0], bv[j][0], acc[i][j], 0, 0, 0);
        acc[i][j] = __builtin_amdgcn_mfma_f32_16x16x32_bf16(a0[i][1], bv[j][1], acc[i][j], 0, 0, 0);
      }
    __builtin_amdgcn_s_setprio(0);
    sbar();

    // ---- Phase B: read a1 -> MFMA rows 64..127, boundary vmcnt ----
#pragma unroll
    for (int i = 0; i < 2; ++i)
#pragma unroll
      for (int kh = 0; kh < 2; ++kh) {
        const int r = wm * 64 + (2 + i) * 16 + lr;
        const int u = (kh * 4 + uo) ^ (lr & 7);
        a1[i][kh] = *(const bf16x8*)&Asb[r * 64 + u * 8];
      }
    __builtin_amdgcn_sched_barrier(0);
    __builtin_amdgcn_s_barrier();
    wait_lgkm0();
    __builtin_amdgcn_sched_barrier(0);
    __builtin_amdgcn_s_setprio(1);
#pragma unroll
    for (int i = 0; i < 2; ++i)
#pragma unroll
      for (int j = 0; j < 4; ++j) {
        acc[2 + i][j] = __builtin_amdgcn_mfma_f32_16x16x32_bf16(a1[i][0], bv[j][0], acc[2 + i][j], 0, 0, 0);
        acc[2 + i][j] = __builtin_amdgcn_mfma_f32_16x16x32_bf16(a1[i][1], bv[j][1], acc[2 + i][j], 0, 0, 0);
      }
    __builtin_amdgcn_s_setprio(0);
    __builtin_amdgcn_sched_barrier(0);
    if (t < NT - 2) wait_vmcnt<6>();
    else            wait_vmcnt<0>();
    __builtin_amdgcn_s_barrier();
    __builtin_amdgcn_sched_barrier(0);
    cur = (cur == 2) ? 0 : cur + 1;
  }

#pragma unroll
  for (int f = 0; f < 4; ++f) {
    const int r0 = bm + wm * 64 + f * 16 + (lane >> 4) * 4;
#pragma unroll
    for (int g = 0; g < 4; ++g) {
      const int c = bn + wn * 64 + g * 16 + (lane & 15);
      float bvs = 0.f;
      if (MODE == 4) bvs = bias[c];
#pragma unroll
      for (int r = 0; r < 4; ++r) {
        const size_t idx = (size_t)(r0 + r) * N + c;
        float v = acc[f][g][r];
        if (MODE == 1 || MODE == 2) v += res[idx];
        if (MODE == 4) v += bvs + res[idx];
        if (MODE == 0 || MODE == 1) outB[idx] = (bf16)v;
        else outF[idx] = v;
      }
    }
  }
}

// ------- fused Performer chunk-sums + segment scan (block = 1 segment) -------
// grid (8, B*H), 512 threads. Writes scanned CS rows + segment totals.
__global__ __launch_bounds__(512) void perf_cs(
    const bf16* __restrict__ kmat, const bf16* __restrict__ vmat, int ld,
    const float* __restrict__ omega, float* __restrict__ CS,
    float* __restrict__ segtot) {
  const int tid = threadIdx.x;
  const int bh = blockIdx.y, b = bh >> 4, h = bh & 15;
  const int seg = blockIdx.x;
  const int s0 = seg * 512;
  __shared__ __align__(16) bf16 vs[512][64];   // XOR-swizzled, 64 KB
  __shared__ float kps[512][8];                // 16 KB
  __shared__ float oms[448];

  {
    const bf16* vb = vmat + ((size_t)(b * Sq + s0)) * ld + h * 64;
#pragma unroll
    for (int p = 0; p < 8; ++p) {
      const int row = p * 64 + (tid >> 3), c16 = (tid & 7) * 8;
      *(uint4*)&vs[row][c16 ^ ((row & 7) * 8)] =
          *(const uint4*)&vb[(size_t)row * ld + c16];
    }
  }
  if (tid < 448) oms[tid] = omega[tid];
  __syncthreads();

  // kp features: one sequence row per thread
  {
    const int row = tid;
    const bf16* kr = kmat + ((size_t)(b * Sq + s0 + row)) * ld + h * 64;
    bf16x8 kv[8];
#pragma unroll
    for (int q = 0; q < 8; ++q) kv[q] = *(const bf16x8*)&kr[q * 8];
    float f[NB];
#pragma unroll
    for (int n = 0; n < NB; ++n) f[n] = 0.f;
#pragma unroll
    for (int d = 0; d < 64; ++d) {
      const float kd = (float)kv[d >> 3][d & 7];
#pragma unroll
      for (int n = 0; n < NB; ++n) f[n] += kd * oms[n * 64 + d];
    }
    float sum = 1e-6f, e[NB];
#pragma unroll
    for (int n = 0; n < NB; ++n) { e[n] = __expf(-0.5f * f[n] * f[n]); sum += e[n]; }
    const float inv = 1.f / sum;
#pragma unroll
    for (int n = 0; n < NB; ++n) kps[row][n] = e[n] * inv;
    kps[row][7] = 0.f;
  }
  __syncthreads();

  // inclusive scan over the segment's 128 chunks; one state component/thread
  if (tid < CSW) {
    const int comp = tid;
    float* outb = CS + ((size_t)bh * NCH + seg * 128) * CSW;
    float r = 0.f;
    if (comp < 8) {
      for (int c = 0; c < 128; ++c) {
        if (comp < 7)
          r += kps[4*c][comp] + kps[4*c+1][comp] + kps[4*c+2][comp] + kps[4*c+3][comp];
        outb[(size_t)c * CSW + comp] = r;
      }
    } else if (comp < 456) {
      const int n = (comp - 8) >> 6, d = (comp - 8) & 63;
      for (int c = 0; c < 128; ++c) {
#pragma unroll
        for (int i = 0; i < 4; ++i) {
          const int row = 4 * c + i;
          r += kps[row][n] * (float)vs[row][d ^ ((row & 7) * 8)];
        }
        outb[(size_t)c * CSW + comp] = r;
      }
    } else {
      for (int c = 0; c < 128; ++c) outb[(size_t)c * CSW + comp] = 0.f;
    }
    segtot[((size_t)bh * 8 + seg) * CSW + comp] = r;
  }
}

// ---------------- exclusive scan of the 8 segment totals ----------------
__global__ __launch_bounds__(256) void perf_scan2(float* __restrict__ segtot) {
  const int bh = blockIdx.x;
  const int c0 = threadIdx.x;
  float run0 = 0.f, run1 = 0.f;
#pragma unroll
  for (int s = 0; s < 8; ++s) {
    float* st = segtot + ((size_t)bh * 8 + s) * CSW;
    float t0 = st[c0]; st[c0] = run0; run0 += t0;
    if (c0 + 256 < CSW) { float t1 = st[c0 + 256]; st[c0 + 256] = run1; run1 += t1; }
  }
}

// ---------------- Performer output ----------------
__global__ __launch_bounds__(256) void perf_out(
    const bf16* __restrict__ qmat, int ldq, const float* __restrict__ omega,
    const float* __restrict__ CS, const float* __restrict__ segtot,
    bf16* __restrict__ attn) {
  const int tid = threadIdx.x;
  const int bh = blockIdx.y, b = bh >> 4, h = bh & 15;
  const int s0 = blockIdx.x * 128;
  const int cg0 = s0 >> 2;
  const int seg = cg0 >> 7;
  __shared__ __align__(16) float Ps[32 * CSW];
  __shared__ float qps[128][8];
  __shared__ float oms[NB * 64];

  {
    const float* src = CS + ((size_t)bh * NCH + cg0) * CSW;
    const float* off = segtot + ((size_t)bh * 8 + seg) * CSW;
    for (int i = tid; i < 32 * CSW / 4; i += 256) {
      f32x4 a = *(const f32x4*)&src[i * 4];
      f32x4 o = *(const f32x4*)&off[(i % (CSW / 4)) * 4];
      a += o;
      *(f32x4*)&Ps[i * 4] = a;
    }
  }
  if (tid < 224) { oms[tid] = omega[tid]; oms[tid + 224] = omega[tid + 224]; }
  __syncthreads();
  {
    const int p = tid >> 1, half = tid & 1;
    const bf16* qr = qmat + ((size_t)(b * Sq + s0 + p)) * ldq + h * 64 + half * 32;
    bf16x8 qv[4];
#pragma unroll
    for (int q = 0; q < 4; ++q) qv[q] = *(const bf16x8*)&qr[q * 8];
    float f[NB];
#pragma unroll
    for (int n = 0; n < NB; ++n) f[n] = 0.f;
#pragma unroll
    for (int d = 0; d < 32; ++d) {
      float qd = (float)qv[d >> 3][d & 7];
#pragma unroll
      for (int n = 0; n < NB; ++n) f[n] += qd * oms[n * 64 + half * 32 + d];
    }
    float sum = 1e-6f;
    float e[NB];
#pragma unroll
    for (int n = 0; n < NB; ++n) {
      float full = f[n] + __shfl_xor(f[n], 1);
      e[n] = __expf(-0.5f * full * full);
      sum += e[n];
    }
    float inv = 1.f / sum;
    if (half == 0) {
      float den = 1e-6f;
      const float* Pr = &Ps[(p >> 2) * CSW];
#pragma unroll
      for (int n = 0; n < NB; ++n) {
        float qn = e[n] * inv;
        qps[p][n] = qn;
        den += qn * Pr[n];
      }
      qps[p][7] = 1.f / den;
    }
  }
  __syncthreads();
  {
    const int d = tid & 63, w = tid >> 6;
    for (int qq = w; qq < 128; qq += 4) {
      const float* Pr = &Ps[(qq >> 2) * CSW + 8 + d];
      float num = 0.f;
#pragma unroll
      for (int n = 0; n < NB; ++n) num += qps[qq][n] * Pr[n * 64];
      attn[((size_t)(b * Sq + s0 + qq)) * Dm + h * 64 + d] = (bf16)(num * qps[qq][7]);
    }
  }
}

// ---------------------------------------------------------------------------
extern "C" void kernel_launch(void* const* d_in, const int* in_sizes, int n_in,
                              void* d_out, int out_size, void* d_ws, size_t ws_size,
                              hipStream_t stream) {
  const float* x    = (const float*)d_in[0];
  const float* lto  = (const float*)d_in[1];
  const float* w_s[4] = {(const float*)d_in[2], (const float*)d_in[3],
                         (const float*)d_in[4], (const float*)d_in[5]};
  const float* w_c[4] = {(const float*)d_in[6], (const float*)d_in[7],
                         (const float*)d_in[8], (const float*)d_in[9]};
  const float* omega_s = (const float*)d_in[10];
  const float* omega_c = (const float*)d_in[11];
  const float* w1 = (const float*)d_in[12];
  const float* b1 = (const float*)d_in[13];
  const float* w2 = (const float*)d_in[14];
  const float* b2 = (const float*)d_in[15];
  const float* ln_a[3] = {(const float*)d_in[16], (const float*)d_in[18], (const float*)d_in[20]};
  const float* ln_b[3] = {(const float*)d_in[17], (const float*)d_in[19], (const float*)d_in[21]};

  char* ws = (char*)d_ws;
  size_t off = 0;
  auto alloc = [&](size_t bytes) -> char* {
    char* p = ws + off;
    off += (bytes + 255) & ~(size_t)255;
    return p;
  };

  const size_t actB = (size_t)Mrows * Dm * sizeof(bf16);     // 16 MiB
  const size_t MB32 = (size_t)Mrows * 2048 * sizeof(bf16);   // 32 MiB

  bf16* wqkv = (bf16*)alloc((size_t)3072 * 1024 * 2);
  bf16* wo_sb = (bf16*)alloc((size_t)1024 * 1024 * 2);
  bf16* wq_cb = (bf16*)alloc((size_t)1024 * 1024 * 2);
  bf16* wkv  = (bf16*)alloc((size_t)2048 * 1024 * 2);
  bf16* wo_cb = (bf16*)alloc((size_t)1024 * 1024 * 2);
  bf16* w1b = (bf16*)alloc((size_t)Dff * Dm * 2);
  bf16* w2b = (bf16*)alloc((size_t)Dff * Dm * 2);
  bf16* xnb  = (bf16*)alloc(actB);
  char* pool = alloc((size_t)Mrows * Dff * 2);               // 64 MiB shared pool
  bf16* qkvb = (bf16*)pool;                                  // 48 MiB (phase 1)
  bf16* kvb  = (bf16*)pool;                                  // 32 MiB (phase 2)
  bf16* qb   = (bf16*)(pool + MB32);                         // 16 MiB (phase 2)
  bf16* hb   = (bf16*)pool;                                  // 64 MiB (phase 3)
  bf16* attnb= (bf16*)alloc(actB);
  bf16* x2b  = (bf16*)alloc(actB);
  bf16* ln1b = (bf16*)alloc(actB);
  float* lto2 = (float*)alloc((size_t)Mrows * Dm * 4);
  float* CSb  = (float*)alloc((size_t)32 * NCH * CSW * 4);
  float* stb  = (float*)alloc((size_t)32 * 8 * CSW * 4);
  bf16* fnb = xnb;   // xnb dead after QKV_s GEMM

  // ---- batched weight conversion ----
  {
    CvtA a;
    const float* srcs[10] = {w_s[0], w_s[1], w_s[2], w_s[3], w_c[0],
                             w_c[1], w_c[2], w_c[3], w1, w2};
    bf16* dsts[10] = {wqkv, wqkv + 1048576, wqkv + 2097152, wo_sb, wq_cb,
                      wkv, wkv + 1048576, wo_cb, w1b, w2b};
    const int SM = 262144, LG = 1048576;   // n4 sizes
    int st = 0;
    for (int i = 0; i < 10; ++i) {
      a.s[i] = srcs[i]; a.d[i] = dsts[i]; a.start[i] = st;
      st += (i < 8) ? SM : LG;
    }
    a.start[10] = st;                      // 4194304
    cvt10<<<st / 256, 256, 0, stream>>>(a);
  }

  dim3 gperf(Sq / 128, Bq * 16);
  dim3 gseg(8, Bq * 16);
  const int gQKV = (Mrows / 256) * (3072 / 256);   // 384
  const int gKV  = (Mrows / 256) * (2048 / 256);   // 256
  const int gFF1 = (Mrows / 256) * (4096 / 256);   // 512
  const int gN1k = (Mrows / 128) * (1024 / 256);   // 256

  // --- self performer on x ---
  ln_kernel<<<Mrows, 256, 0, stream>>>(x, ln_a[0], ln_b[0], xnb);
  gemm256<0><<<gQKV, 512, 0, stream>>>(xnb, wqkv, Mrows, 3072, 1024, nullptr, nullptr, nullptr, qkvb);
  perf_cs<<<gseg, 512, 0, stream>>>(qkvb + 1024, qkvb + 2048, 3072, omega_s, CSb, stb);
  perf_scan2<<<32, 256, 0, stream>>>(stb);
  perf_out<<<gperf, 256, 0, stream>>>(qkvb, 3072, omega_s, CSb, stb, attnb);
  gemm128<1><<<gN1k, 512, 0, stream>>>(attnb, wo_sb, Mrows, 1024, 1024, nullptr, x, nullptr, x2b);

  // --- cross performer: q from LN(lto), k/v from updated x ---
  ln_kernel<<<Mrows, 256, 0, stream>>>(lto, ln_a[1], ln_b[1], ln1b);
  gemm128<0><<<gN1k, 512, 0, stream>>>(ln1b, wq_cb, Mrows, 1024, 1024, nullptr, nullptr, nullptr, qb);
  gemm256<0><<<gKV, 512, 0, stream>>>(x2b, wkv, Mrows, 2048, 1024, nullptr, nullptr, nullptr, kvb);
  perf_cs<<<gseg, 512, 0, stream>>>(kvb, kvb + 1024, 2048, omega_c, CSb, stb);
  perf_scan2<<<32, 256, 0, stream>>>(stb);
  perf_out<<<gperf, 256, 0, stream>>>(qb, 1024, omega_c, CSb, stb, attnb);
  gemm128<2><<<gN1k, 512, 0, stream>>>(attnb, wo_cb, Mrows, 1024, 1024, nullptr, lto, lto2, nullptr);

  // --- FFN ---
  ln_kernel<<<Mrows, 256, 0, stream>>>(lto2, ln_a[2], ln_b[2], fnb);
  gemm256<3><<<gFF1, 512, 0, stream>>>(fnb, w1b, Mrows, 4096, 1024, b1, nullptr, nullptr, hb);
  gemm128<4><<<gN1k, 512, 0, stream>>>(hb, w2b, Mrows, 1024, 4096, b2, lto2, (float*)d_out, nullptr);
}

// Round 4
// 533.216 us; speedup vs baseline: 1.5321x; 1.1193x over previous
//
#include <hip/hip_runtime.h>
#include <cstdint>
#include <cstddef>

typedef __bf16 bf16;
typedef __bf16 bf16x8 __attribute__((ext_vector_type(8)));
typedef __bf16 bf16x4 __attribute__((ext_vector_type(4)));
typedef float  f32x4  __attribute__((ext_vector_type(4)));

#define NB 7
static constexpr int Bq = 2, Sq = 4096, Dm = 1024, Dff = 4096;
static constexpr int Mrows = Bq * Sq;     // 8192
static constexpr int NCH = Sq / 4;        // 1024 chunks per (b,h)
static constexpr int CSW = 464;           // padded prefix-state row width

__device__ __forceinline__ void gload16(const void* g, void* l) {
  __builtin_amdgcn_global_load_lds((__attribute__((address_space(1))) void*)g,
                                   (__attribute__((address_space(3))) void*)l,
                                   16, 0, 0);
}

template <int N> __device__ __forceinline__ void wait_vmcnt() {
  asm volatile("s_waitcnt vmcnt(%0)" :: "n"(N) : "memory");
}
__device__ __forceinline__ void wait_lgkm0() {
  asm volatile("s_waitcnt lgkmcnt(0)" ::: "memory");
}

__device__ __forceinline__ float gelu_f(float x) {
  const float c = 0.79788456080286535588f;
  float z = c * (x + 0.044715f * x * x * x);
  float t = 1.f - 2.f / (__expf(2.f * z) + 1.f);   // tanh(z)
  return 0.5f * x * (1.f + t);
}

// ---------------- batched f32 -> bf16 convert (10 regions, 1 launch) ----------
struct CvtA {
  const float* s[10];
  bf16* d[10];
  int start[11];   // region boundaries in n4 units (multiples of 256)
};
__global__ __launch_bounds__(256) void cvt10(CvtA a) {
  const int i = blockIdx.x * 256 + threadIdx.x;
  int r = 0;
#pragma unroll
  for (int k = 1; k < 10; ++k) r += (i >= a.start[k]);
  const int o = i - a.start[r];
  f32x4 v = *(const f32x4*)&a.s[r][(size_t)o * 4];
  bf16x4 ov;
#pragma unroll
  for (int e = 0; e < 4; ++e) ov[e] = (bf16)v[e];
  *(bf16x4*)&a.d[r][(size_t)o * 4] = ov;
}

// ---------------- LayerNorm (ddof=1, /(std+eps)) -> bf16 ----------------
__global__ __launch_bounds__(256) void ln_kernel(const float* __restrict__ x,
                                                 const float* __restrict__ alpha,
                                                 const float* __restrict__ beta,
                                                 bf16* __restrict__ out) {
  const int row = blockIdx.x, tid = threadIdx.x;
  const float* xr = x + (size_t)row * Dm;
  f32x4 v = *(const f32x4*)&xr[tid * 4];
  float s  = v[0] + v[1] + v[2] + v[3];
  float s2 = v[0]*v[0] + v[1]*v[1] + v[2]*v[2] + v[3]*v[3];
#pragma unroll
  for (int o = 32; o > 0; o >>= 1) { s += __shfl_xor(s, o); s2 += __shfl_xor(s2, o); }
  __shared__ float red[8];
  const int wid = tid >> 6, lane = tid & 63;
  if (lane == 0) { red[wid] = s; red[wid + 4] = s2; }
  __syncthreads();
  s  = red[0] + red[1] + red[2] + red[3];
  s2 = red[4] + red[5] + red[6] + red[7];
  const float mean = s * (1.f / 1024.f);
  float var = (s2 - s * mean) * (1.f / 1023.f);
  var = fmaxf(var, 0.f);
  const float inv = 1.f / (sqrtf(var) + 1e-6f);
  f32x4 a4 = *(const f32x4*)&alpha[tid * 4];
  f32x4 b4 = *(const f32x4*)&beta[tid * 4];
  bf16x4 o4;
#pragma unroll
  for (int e = 0; e < 4; ++e) o4[e] = (bf16)(a4[e] * (v[e] - mean) * inv + b4[e]);
  *(bf16x4*)&out[(size_t)row * Dm + tid * 4] = o4;
}

// ------------- 128x128 double-buffered GEMM, 256 threads, 2 blocks/CU -------------
// C[M,N] = A[M,K] @ W[N,K]^T. 4 waves (2x2), per-wave 64x64, BK=64.
// Per tile: 16 ds_read_b128 -> lgkm0 -> barrier -> stage(t+2, 8 gloads) -> 32 MFMA
// -> vmcnt(8) -> barrier. No full vmcnt drain in steady state; 64 KB LDS so two
// independent blocks per CU overlap each other's read/drain phases.
// MODE 0: out bf16 | 1: +res(f32)->bf16 | 2: +res(f32)->f32 | 3: +bias,gelu->bf16
// MODE 4: +bias+res(f32)->f32
template <int MODE>
__global__ __launch_bounds__(256, 2) void gemm128(
    const bf16* __restrict__ A, const bf16* __restrict__ Bw,
    int M, int N, int K,
    const float* __restrict__ bias, const float* __restrict__ res,
    float* __restrict__ outF, bf16* __restrict__ outB) {
  constexpr int BM = 128, BN = 128;
  __shared__ __align__(16) bf16 As[2][BM * 64];   // 32 KB
  __shared__ __align__(16) bf16 Bs[2][BN * 64];   // 32 KB

  const int tid = threadIdx.x;
  const int lane = tid & 63, wid = tid >> 6;
  const int wm = wid >> 1, wn = wid & 1;

  int bid = blockIdx.x;
  const int nwg = gridDim.x;
  bid = (bid & 7) * (nwg >> 3) + (bid >> 3);   // XCD swizzle (nwg % 8 == 0)
  const int nbx = N / BN;
  const int bm = (bid / nbx) * BM, bn = (bid % nbx) * BN;
  const int NT = K >> 6;

  const int srow = tid >> 3;                       // 0..31
  const int scol = ((tid & 7) ^ (srow & 7)) * 8;   // inverse-swizzled k offset
  const bf16* Ag = A  + (size_t)(bm + srow) * K + scol;
  const bf16* Bg = Bw + (size_t)(bn + srow) * K + scol;

  f32x4 acc[4][4] = {};
  const int lr = lane & 15, uo = lane >> 4;

  auto stA = [&](int buf, int t) {
#pragma unroll
    for (int c = 0; c < 4; ++c)
      gload16(Ag + ((size_t)(c * 32) * K + (size_t)t * 64),
              (char*)(&As[buf][0]) + c * 4096 + wid * 1024);
  };
  auto stB = [&](int buf, int t) {
#pragma unroll
    for (int c = 0; c < 4; ++c)
      gload16(Bg + ((size_t)(c * 32) * K + (size_t)t * 64),
              (char*)(&Bs[buf][0]) + c * 4096 + wid * 1024);
  };

  // prologue: stage tiles 0 and 1
  stA(0, 0); stB(0, 0);
  stA(1, 1); stB(1, 1);
  wait_vmcnt<8>();   // own tile-0 loads retired
  __builtin_amdgcn_s_barrier();   // => all waves' tile-0 loads retired

  bf16x8 a[4][2], b[4][2];

  for (int t = 0; t < NT; ++t) {
    const int cur = t & 1;
    const bf16* Asb = &As[cur][0];
    const bf16* Bsb = &Bs[cur][0];

    // ---- read all fragments for this tile ----
#pragma unroll
    for (int i = 0; i < 4; ++i)
#pragma unroll
      for (int kh = 0; kh < 2; ++kh) {
        const int r = wm * 64 + i * 16 + lr;
        const int u = (kh * 4 + uo) ^ (lr & 7);
        a[i][kh] = *(const bf16x8*)&Asb[r * 64 + u * 8];
      }
#pragma unroll
    for (int j = 0; j < 4; ++j)
#pragma unroll
      for (int kh = 0; kh < 2; ++kh) {
        const int r = wn * 64 + j * 16 + lr;
        const int u = (kh * 4 + uo) ^ (lr & 7);
        b[j][kh] = *(const bf16x8*)&Bsb[r * 64 + u * 8];
      }
    wait_lgkm0();                          // own reads of buf[cur] complete
    __builtin_amdgcn_sched_barrier(0);
    __builtin_amdgcn_s_barrier();          // all waves' reads complete
    __builtin_amdgcn_sched_barrier(0);

    // ---- stage tile t+2 into the buffer just read (race-free) ----
    if (t + 2 < NT) { stA(cur, t + 2); stB(cur, t + 2); }
    __builtin_amdgcn_sched_barrier(0);

    // ---- MFMA ----
    __builtin_amdgcn_s_setprio(1);
#pragma unroll
    for (int i = 0; i < 4; ++i)
#pragma unroll
      for (int j = 0; j < 4; ++j) {
        acc[i][j] = __builtin_amdgcn_mfma_f32_16x16x32_bf16(a[i][0], b[j][0], acc[i][j], 0, 0, 0);
        acc[i][j] = __builtin_amdgcn_mfma_f32_16x16x32_bf16(a[i][1], b[j][1], acc[i][j], 0, 0, 0);
      }
    __builtin_amdgcn_s_setprio(0);
    __builtin_amdgcn_sched_barrier(0);

    // ---- tile boundary: next tile staged, 1 tile in flight ----
    if (t < NT - 2) wait_vmcnt<8>();
    else            wait_vmcnt<0>();
    __builtin_amdgcn_s_barrier();
    __builtin_amdgcn_sched_barrier(0);
  }

  // ---- epilogue ----
#pragma unroll
  for (int f = 0; f < 4; ++f) {
    const int r0 = bm + wm * 64 + f * 16 + (lane >> 4) * 4;
#pragma unroll
    for (int g = 0; g < 4; ++g) {
      const int c = bn + wn * 64 + g * 16 + (lane & 15);
      float bv = 0.f;
      if (MODE == 3 || MODE == 4) bv = bias[c];
#pragma unroll
      for (int r = 0; r < 4; ++r) {
        const size_t idx = (size_t)(r0 + r) * N + c;
        float v = acc[f][g][r];
        if (MODE == 1 || MODE == 2) v += res[idx];
        if (MODE == 3) v = gelu_f(v + bv);
        if (MODE == 4) v += bv + res[idx];
        if (MODE == 0 || MODE == 1 || MODE == 3) outB[idx] = (bf16)v;
        else outF[idx] = v;
      }
    }
  }
}

// ------- fused Performer chunk-sums + segment scan (block = 1 segment) -------
// grid (8, B*H), 512 threads. Writes scanned CS rows + segment totals.
__global__ __launch_bounds__(512) void perf_cs(
    const bf16* __restrict__ kmat, const bf16* __restrict__ vmat, int ld,
    const float* __restrict__ omega, float* __restrict__ CS,
    float* __restrict__ segtot) {
  const int tid = threadIdx.x;
  const int bh = blockIdx.y, b = bh >> 4, h = bh & 15;
  const int seg = blockIdx.x;
  const int s0 = seg * 512;
  __shared__ __align__(16) bf16 vs[512][64];   // XOR-swizzled, 64 KB
  __shared__ float kps[512][8];                // 16 KB
  __shared__ float oms[448];

  {
    const bf16* vb = vmat + ((size_t)(b * Sq + s0)) * ld + h * 64;
#pragma unroll
    for (int p = 0; p < 8; ++p) {
      const int row = p * 64 + (tid >> 3), c16 = (tid & 7) * 8;
      *(uint4*)&vs[row][c16 ^ ((row & 7) * 8)] =
          *(const uint4*)&vb[(size_t)row * ld + c16];
    }
  }
  if (tid < 448) oms[tid] = omega[tid];
  __syncthreads();

  // kp features: one sequence row per thread
  {
    const int row = tid;
    const bf16* kr = kmat + ((size_t)(b * Sq + s0 + row)) * ld + h * 64;
    bf16x8 kv[8];
#pragma unroll
    for (int q = 0; q < 8; ++q) kv[q] = *(const bf16x8*)&kr[q * 8];
    float f[NB];
#pragma unroll
    for (int n = 0; n < NB; ++n) f[n] = 0.f;
#pragma unroll
    for (int d = 0; d < 64; ++d) {
      const float kd = (float)kv[d >> 3][d & 7];
#pragma unroll
      for (int n = 0; n < NB; ++n) f[n] += kd * oms[n * 64 + d];
    }
    float sum = 1e-6f, e[NB];
#pragma unroll
    for (int n = 0; n < NB; ++n) { e[n] = __expf(-0.5f * f[n] * f[n]); sum += e[n]; }
    const float inv = 1.f / sum;
#pragma unroll
    for (int n = 0; n < NB; ++n) kps[row][n] = e[n] * inv;
    kps[row][7] = 0.f;
  }
  __syncthreads();

  // inclusive scan over the segment's 128 chunks; one state component/thread
  if (tid < CSW) {
    const int comp = tid;
    float* outb = CS + ((size_t)bh * NCH + seg * 128) * CSW;
    float r = 0.f;
    if (comp < 8) {
      for (int c = 0; c < 128; ++c) {
        if (comp < 7)
          r += kps[4*c][comp] + kps[4*c+1][comp] + kps[4*c+2][comp] + kps[4*c+3][comp];
        outb[(size_t)c * CSW + comp] = r;
      }
    } else if (comp < 456) {
      const int n = (comp - 8) >> 6, d = (comp - 8) & 63;
      for (int c = 0; c < 128; ++c) {
#pragma unroll
        for (int i = 0; i < 4; ++i) {
          const int row = 4 * c + i;
          r += kps[row][n] * (float)vs[row][d ^ ((row & 7) * 8)];
        }
        outb[(size_t)c * CSW + comp] = r;
      }
    } else {
      for (int c = 0; c < 128; ++c) outb[(size_t)c * CSW + comp] = 0.f;
    }
    segtot[((size_t)bh * 8 + seg) * CSW + comp] = r;
  }
}

// ---------------- exclusive scan of the 8 segment totals ----------------
__global__ __launch_bounds__(256) void perf_scan2(float* __restrict__ segtot) {
  const int bh = blockIdx.x;
  const int c0 = threadIdx.x;
  float run0 = 0.f, run1 = 0.f;
#pragma unroll
  for (int s = 0; s < 8; ++s) {
    float* st = segtot + ((size_t)bh * 8 + s) * CSW;
    float t0 = st[c0]; st[c0] = run0; run0 += t0;
    if (c0 + 256 < CSW) { float t1 = st[c0 + 256]; st[c0 + 256] = run1; run1 += t1; }
  }
}

// ---------------- Performer output ----------------
__global__ __launch_bounds__(256) void perf_out(
    const bf16* __restrict__ qmat, int ldq, const float* __restrict__ omega,
    const float* __restrict__ CS, const float* __restrict__ segtot,
    bf16* __restrict__ attn) {
  const int tid = threadIdx.x;
  const int bh = blockIdx.y, b = bh >> 4, h = bh & 15;
  const int s0 = blockIdx.x * 128;
  const int cg0 = s0 >> 2;
  const int seg = cg0 >> 7;
  __shared__ __align__(16) float Ps[32 * CSW];
  __shared__ float qps[128][8];
  __shared__ float oms[NB * 64];

  {
    const float* src = CS + ((size_t)bh * NCH + cg0) * CSW;
    const float* off = segtot + ((size_t)bh * 8 + seg) * CSW;
    for (int i = tid; i < 32 * CSW / 4; i += 256) {
      f32x4 a = *(const f32x4*)&src[i * 4];
      f32x4 o = *(const f32x4*)&off[(i % (CSW / 4)) * 4];
      a += o;
      *(f32x4*)&Ps[i * 4] = a;
    }
  }
  if (tid < 224) { oms[tid] = omega[tid]; oms[tid + 224] = omega[tid + 224]; }
  __syncthreads();
  {
    const int p = tid >> 1, half = tid & 1;
    const bf16* qr = qmat + ((size_t)(b * Sq + s0 + p)) * ldq + h * 64 + half * 32;
    bf16x8 qv[4];
#pragma unroll
    for (int q = 0; q < 4; ++q) qv[q] = *(const bf16x8*)&qr[q * 8];
    float f[NB];
#pragma unroll
    for (int n = 0; n < NB; ++n) f[n] = 0.f;
#pragma unroll
    for (int d = 0; d < 32; ++d) {
      float qd = (float)qv[d >> 3][d & 7];
#pragma unroll
      for (int n = 0; n < NB; ++n) f[n] += qd * oms[n * 64 + half * 32 + d];
    }
    float sum = 1e-6f;
    float e[NB];
#pragma unroll
    for (int n = 0; n < NB; ++n) {
      float full = f[n] + __shfl_xor(f[n], 1);
      e[n] = __expf(-0.5f * full * full);
      sum += e[n];
    }
    float inv = 1.f / sum;
    if (half == 0) {
      float den = 1e-6f;
      const float* Pr = &Ps[(p >> 2) * CSW];
#pragma unroll
      for (int n = 0; n < NB; ++n) {
        float qn = e[n] * inv;
        qps[p][n] = qn;
        den += qn * Pr[n];
      }
      qps[p][7] = 1.f / den;
    }
  }
  __syncthreads();
  {
    const int d = tid & 63, w = tid >> 6;
    for (int qq = w; qq < 128; qq += 4) {
      const float* Pr = &Ps[(qq >> 2) * CSW + 8 + d];
      float num = 0.f;
#pragma unroll
      for (int n = 0; n < NB; ++n) num += qps[qq][n] * Pr[n * 64];
      attn[((size_t)(b * Sq + s0 + qq)) * Dm + h * 64 + d] = (bf16)(num * qps[qq][7]);
    }
  }
}

// ---------------------------------------------------------------------------
extern "C" void kernel_launch(void* const* d_in, const int* in_sizes, int n_in,
                              void* d_out, int out_size, void* d_ws, size_t ws_size,
                              hipStream_t stream) {
  const float* x    = (const float*)d_in[0];
  const float* lto  = (const float*)d_in[1];
  const float* w_s[4] = {(const float*)d_in[2], (const float*)d_in[3],
                         (const float*)d_in[4], (const float*)d_in[5]};
  const float* w_c[4] = {(const float*)d_in[6], (const float*)d_in[7],
                         (const float*)d_in[8], (const float*)d_in[9]};
  const float* omega_s = (const float*)d_in[10];
  const float* omega_c = (const float*)d_in[11];
  const float* w1 = (const float*)d_in[12];
  const float* b1 = (const float*)d_in[13];
  const float* w2 = (const float*)d_in[14];
  const float* b2 = (const float*)d_in[15];
  const float* ln_a[3] = {(const float*)d_in[16], (const float*)d_in[18], (const float*)d_in[20]};
  const float* ln_b[3] = {(const float*)d_in[17], (const float*)d_in[19], (const float*)d_in[21]};

  char* ws = (char*)d_ws;
  size_t off = 0;
  auto alloc = [&](size_t bytes) -> char* {
    char* p = ws + off;
    off += (bytes + 255) & ~(size_t)255;
    return p;
  };

  const size_t actB = (size_t)Mrows * Dm * sizeof(bf16);     // 16 MiB
  const size_t MB32 = (size_t)Mrows * 2048 * sizeof(bf16);   // 32 MiB

  bf16* wqkv = (bf16*)alloc((size_t)3072 * 1024 * 2);
  bf16* wo_sb = (bf16*)alloc((size_t)1024 * 1024 * 2);
  bf16* wq_cb = (bf16*)alloc((size_t)1024 * 1024 * 2);
  bf16* wkv  = (bf16*)alloc((size_t)2048 * 1024 * 2);
  bf16* wo_cb = (bf16*)alloc((size_t)1024 * 1024 * 2);
  bf16* w1b = (bf16*)alloc((size_t)Dff * Dm * 2);
  bf16* w2b = (bf16*)alloc((size_t)Dff * Dm * 2);
  bf16* xnb  = (bf16*)alloc(actB);
  char* pool = alloc((size_t)Mrows * Dff * 2);               // 64 MiB shared pool
  bf16* qkvb = (bf16*)pool;                                  // 48 MiB (phase 1)
  bf16* kvb  = (bf16*)pool;                                  // 32 MiB (phase 2)
  bf16* qb   = (bf16*)(pool + MB32);                         // 16 MiB (phase 2)
  bf16* hb   = (bf16*)pool;                                  // 64 MiB (phase 3)
  bf16* attnb= (bf16*)alloc(actB);
  bf16* x2b  = (bf16*)alloc(actB);
  bf16* ln1b = (bf16*)alloc(actB);
  float* lto2 = (float*)alloc((size_t)Mrows * Dm * 4);
  float* CSb  = (float*)alloc((size_t)32 * NCH * CSW * 4);
  float* stb  = (float*)alloc((size_t)32 * 8 * CSW * 4);
  bf16* fnb = xnb;   // xnb dead after QKV_s GEMM

  // ---- batched weight conversion ----
  {
    CvtA a;
    const float* srcs[10] = {w_s[0], w_s[1], w_s[2], w_s[3], w_c[0],
                             w_c[1], w_c[2], w_c[3], w1, w2};
    bf16* dsts[10] = {wqkv, wqkv + 1048576, wqkv + 2097152, wo_sb, wq_cb,
                      wkv, wkv + 1048576, wo_cb, w1b, w2b};
    const int SM = 262144, LG = 1048576;   // n4 sizes
    int st = 0;
    for (int i = 0; i < 10; ++i) {
      a.s[i] = srcs[i]; a.d[i] = dsts[i]; a.start[i] = st;
      st += (i < 8) ? SM : LG;
    }
    a.start[10] = st;                      // 4194304
    cvt10<<<st / 256, 256, 0, stream>>>(a);
  }

  dim3 gperf(Sq / 128, Bq * 16);
  dim3 gseg(8, Bq * 16);
  const int gQKV = (Mrows / 128) * (3072 / 128);   // 1536
  const int gKV  = (Mrows / 128) * (2048 / 128);   // 1024
  const int gFF1 = (Mrows / 128) * (4096 / 128);   // 2048
  const int gN1k = (Mrows / 128) * (1024 / 128);   // 512

  // --- self performer on x ---
  ln_kernel<<<Mrows, 256, 0, stream>>>(x, ln_a[0], ln_b[0], xnb);
  gemm128<0><<<gQKV, 256, 0, stream>>>(xnb, wqkv, Mrows, 3072, 1024, nullptr, nullptr, nullptr, qkvb);
  perf_cs<<<gseg, 512, 0, stream>>>(qkvb + 1024, qkvb + 2048, 3072, omega_s, CSb, stb);
  perf_scan2<<<32, 256, 0, stream>>>(stb);
  perf_out<<<gperf, 256, 0, stream>>>(qkvb, 3072, omega_s, CSb, stb, attnb);
  gemm128<1><<<gN1k, 256, 0, stream>>>(attnb, wo_sb, Mrows, 1024, 1024, nullptr, x, nullptr, x2b);

  // --- cross performer: q from LN(lto), k/v from updated x ---
  ln_kernel<<<Mrows, 256, 0, stream>>>(lto, ln_a[1], ln_b[1], ln1b);
  gemm128<0><<<gN1k, 256, 0, stream>>>(ln1b, wq_cb, Mrows, 1024, 1024, nullptr, nullptr, nullptr, qb);
  gemm128<0><<<gKV, 256, 0, stream>>>(x2b, wkv, Mrows, 2048, 1024, nullptr, nullptr, nullptr, kvb);
  perf_cs<<<gseg, 512, 0, stream>>>(kvb, kvb + 1024, 2048, omega_c, CSb, stb);
  perf_scan2<<<32, 256, 0, stream>>>(stb);
  perf_out<<<gperf, 256, 0, stream>>>(qb, 1024, omega_c, CSb, stb, attnb);
  gemm128<2><<<gN1k, 256, 0, stream>>>(attnb, wo_cb, Mrows, 1024, 1024, nullptr, lto, lto2, nullptr);

  // --- FFN ---
  ln_kernel<<<Mrows, 256, 0, stream>>>(lto2, ln_a[2], ln_b[2], fnb);
  gemm128<3><<<gFF1, 256, 0, stream>>>(fnb, w1b, Mrows, 4096, 1024, b1, nullptr, nullptr, hb);
  gemm128<4><<<gN1k, 256, 0, stream>>>(hb, w2b, Mrows, 1024, 4096, b2, lto2, (float*)d_out, nullptr);
}

// Round 5
// 531.921 us; speedup vs baseline: 1.5358x; 1.0024x over previous
//
#include <hip/hip_runtime.h>
#include <cstdint>
#include <cstddef>

typedef __bf16 bf16;
typedef __bf16 bf16x8 __attribute__((ext_vector_type(8)));
typedef __bf16 bf16x4 __attribute__((ext_vector_type(4)));
typedef float  f32x4  __attribute__((ext_vector_type(4)));

#define NB 7
static constexpr int Bq = 2, Sq = 4096, Dm = 1024, Dff = 4096;
static constexpr int Mrows = Bq * Sq;     // 8192
static constexpr int NCH = Sq / 4;        // 1024 chunks per (b,h)
static constexpr int CSW = 464;           // padded prefix-state row width

__device__ __forceinline__ void gload16(const void* g, void* l) {
  __builtin_amdgcn_global_load_lds((__attribute__((address_space(1))) void*)g,
                                   (__attribute__((address_space(3))) void*)l,
                                   16, 0, 0);
}

template <int N> __device__ __forceinline__ void wait_vmcnt() {
  asm volatile("s_waitcnt vmcnt(%0)" :: "n"(N) : "memory");
}
__device__ __forceinline__ void wait_lgkm0() {
  asm volatile("s_waitcnt lgkmcnt(0)" ::: "memory");
}
__device__ __forceinline__ void sbar() {
  __builtin_amdgcn_sched_barrier(0);
  __builtin_amdgcn_s_barrier();
  __builtin_amdgcn_sched_barrier(0);
}

__device__ __forceinline__ float gelu_f(float x) {
  const float c = 0.79788456080286535588f;
  float z = c * (x + 0.044715f * x * x * x);
  float t = 1.f - 2.f / (__expf(2.f * z) + 1.f);   // tanh(z)
  return 0.5f * x * (1.f + t);
}

// ---------------- batched f32 -> bf16 convert (10 regions, 1 launch) ----------
struct CvtA {
  const float* s[10];
  bf16* d[10];
  int start[11];
};
__global__ __launch_bounds__(256) void cvt10(CvtA a) {
  const int i = blockIdx.x * 256 + threadIdx.x;
  int r = 0;
#pragma unroll
  for (int k = 1; k < 10; ++k) r += (i >= a.start[k]);
  const int o = i - a.start[r];
  f32x4 v = *(const f32x4*)&a.s[r][(size_t)o * 4];
  bf16x4 ov;
#pragma unroll
  for (int e = 0; e < 4; ++e) ov[e] = (bf16)v[e];
  *(bf16x4*)&a.d[r][(size_t)o * 4] = ov;
}

// ---------------- LayerNorm (ddof=1, /(std+eps)) -> bf16 ----------------
__global__ __launch_bounds__(256) void ln_kernel(const float* __restrict__ x,
                                                 const float* __restrict__ alpha,
                                                 const float* __restrict__ beta,
                                                 bf16* __restrict__ out) {
  const int row = blockIdx.x, tid = threadIdx.x;
  const float* xr = x + (size_t)row * Dm;
  f32x4 v = *(const f32x4*)&xr[tid * 4];
  float s  = v[0] + v[1] + v[2] + v[3];
  float s2 = v[0]*v[0] + v[1]*v[1] + v[2]*v[2] + v[3]*v[3];
#pragma unroll
  for (int o = 32; o > 0; o >>= 1) { s += __shfl_xor(s, o); s2 += __shfl_xor(s2, o); }
  __shared__ float red[8];
  const int wid = tid >> 6, lane = tid & 63;
  if (lane == 0) { red[wid] = s; red[wid + 4] = s2; }
  __syncthreads();
  s  = red[0] + red[1] + red[2] + red[3];
  s2 = red[4] + red[5] + red[6] + red[7];
  const float mean = s * (1.f / 1024.f);
  float var = (s2 - s * mean) * (1.f / 1023.f);
  var = fmaxf(var, 0.f);
  const float inv = 1.f / (sqrtf(var) + 1e-6f);
  f32x4 a4 = *(const f32x4*)&alpha[tid * 4];
  f32x4 b4 = *(const f32x4*)&beta[tid * 4];
  bf16x4 o4;
#pragma unroll
  for (int e = 0; e < 4; ++e) o4[e] = (bf16)(a4[e] * (v[e] - mean) * inv + b4[e]);
  *(bf16x4*)&out[(size_t)row * Dm + tid * 4] = o4;
}

// ============ 256x256 8-phase GEMM (m201 template), 512 thr, 8 waves 2x4 ============
// Per iter: 2 K-tiles (even->buf0, odd->buf1). Each phase: quadrant ds-reads +
// 1 half-tile stage (2 gload_lds) + barrier + lgkm0 + 16 MFMA + barrier.
// Stage map: P1:Bhi(odd) P2:Ahi(odd) P3:Blo(e') P4:Alo(e') P5:Bhi(e') P6:Ahi(e')
// P7:Blo(o') P8:Alo(o').  vmcnt(4) at P4/P8 only (P4 of last iter: vmcnt(0)).
// MODE 0: out bf16 | 3: +bias,gelu->bf16
template <int MODE>
__global__ __launch_bounds__(512, 2) void gemm256(
    const bf16* __restrict__ A, const bf16* __restrict__ Bw,
    int M, int N, int K,
    const float* __restrict__ bias, bf16* __restrict__ outB) {
  __shared__ __align__(16) bf16 As[2][256 * 64];   // 64 KB
  __shared__ __align__(16) bf16 Bs[2][256 * 64];   // 64 KB

  const int tid = threadIdx.x;
  const int lane = tid & 63, wid = tid >> 6;
  const int wm = wid >> 2, wn = wid & 3;

  int bid = blockIdx.x;
  const int nwg = gridDim.x;
  bid = (bid & 7) * (nwg >> 3) + (bid >> 3);   // XCD swizzle (nwg % 8 == 0)
  const int nbx = N >> 8;
  const int bm = (bid / nbx) * 256, bn = (bid % nbx) * 256;
  const int NT = K >> 6, NI = NT >> 1;

  const int srow = tid >> 3;                       // 0..63
  const int scol = ((tid & 7) ^ (srow & 7)) * 8;   // inverse-swizzled k offset
  const bf16* Ag = A  + (size_t)(bm + srow) * K + scol;
  const bf16* Bg = Bw + (size_t)(bn + srow) * K + scol;

  auto stA = [&](int buf, int H, int t) {
#pragma unroll
    for (int c = 0; c < 2; ++c)
      gload16(Ag + (size_t)(H * 128 + c * 64) * K + (size_t)t * 64,
              (char*)(&As[buf][0]) + H * 16384 + c * 8192 + wid * 1024);
  };
  auto stB = [&](int buf, int H, int t) {
#pragma unroll
    for (int c = 0; c < 2; ++c)
      gload16(Bg + (size_t)(H * 128 + c * 64) * K + (size_t)t * 64,
              (char*)(&Bs[buf][0]) + H * 16384 + c * 8192 + wid * 1024);
  };

  f32x4 acc[8][4] = {};
  const int lr = lane & 15, uo = lane >> 4;

  auto ldA = [&](const bf16* Asb, int mh, bf16x8 (&a)[4][2]) {
#pragma unroll
    for (int i = 0; i < 4; ++i)
#pragma unroll
      for (int kh = 0; kh < 2; ++kh) {
        const int r = wm * 128 + mh * 64 + i * 16 + lr;
        const int u = (kh * 4 + uo) ^ (lr & 7);
        a[i][kh] = *(const bf16x8*)&Asb[r * 64 + u * 8];
      }
  };
  auto ldB = [&](const bf16* Bsb, int nh, bf16x8 (&b)[2][2]) {
#pragma unroll
    for (int j = 0; j < 2; ++j)
#pragma unroll
      for (int kh = 0; kh < 2; ++kh) {
        const int r = wn * 64 + nh * 32 + j * 16 + lr;
        const int u = (kh * 4 + uo) ^ (lr & 7);
        b[j][kh] = *(const bf16x8*)&Bsb[r * 64 + u * 8];
      }
  };
  auto mm = [&](int mh, int nh, bf16x8 (&a)[4][2], bf16x8 (&b)[2][2]) {
    __builtin_amdgcn_s_setprio(1);
#pragma unroll
    for (int i = 0; i < 4; ++i)
#pragma unroll
      for (int j = 0; j < 2; ++j) {
        acc[mh*4+i][nh*2+j] = __builtin_amdgcn_mfma_f32_16x16x32_bf16(
            a[i][0], b[j][0], acc[mh*4+i][nh*2+j], 0, 0, 0);
        acc[mh*4+i][nh*2+j] = __builtin_amdgcn_mfma_f32_16x16x32_bf16(
            a[i][1], b[j][1], acc[mh*4+i][nh*2+j], 0, 0, 0);
      }
    __builtin_amdgcn_s_setprio(0);
  };

  // prologue: tile 0 full, tile 1 lo-halves
  stB(0, 0, 0); stB(0, 1, 0); stA(0, 0, 0); stA(0, 1, 0);
  stB(1, 0, 1); stA(1, 0, 1);
  wait_vmcnt<4>();
  __builtin_amdgcn_s_barrier();

  for (int t = 0; t < NI; ++t) {
    const int u = 2 * t;
    const bool more = (t + 1 < NI);
#pragma unroll
    for (int hf = 0; hf < 2; ++hf) {
      const bf16* Asb = &As[hf][0];
      const bf16* Bsb = &Bs[hf][0];
      bf16x8 a[4][2], b0[2][2], b1[2][2];

      // ---- P1 / P5 ----
      ldA(Asb, 0, a); ldB(Bsb, 0, b0);
      __builtin_amdgcn_sched_barrier(0);
      if (hf == 0) stB(1, 1, u + 1);
      else if (more) stB(0, 1, u + 2);
      sbar();
      wait_lgkm0();
      __builtin_amdgcn_sched_barrier(0);
      mm(0, 0, a, b0);
      sbar();

      // ---- P2 / P6 ----
      ldB(Bsb, 1, b1);
      __builtin_amdgcn_sched_barrier(0);
      if (hf == 0) stA(1, 1, u + 1);
      else if (more) stA(0, 1, u + 2);
      sbar();
      wait_lgkm0();
      __builtin_amdgcn_sched_barrier(0);
      mm(0, 1, a, b1);
      sbar();

      // ---- P3 / P7 ----
      ldA(Asb, 1, a);   // reload A regs for m-half 1 (frees pressure)
      __builtin_amdgcn_sched_barrier(0);
      if (more) { if (hf == 0) stB(0, 0, u + 2); else stB(1, 0, u + 3); }
      sbar();
      wait_lgkm0();
      __builtin_amdgcn_sched_barrier(0);
      mm(1, 1, a, b1);
      sbar();

      // ---- P4 / P8 ----
      if (more) { if (hf == 0) stA(0, 0, u + 2); else stA(1, 0, u + 3); }
      __builtin_amdgcn_sched_barrier(0);
      sbar();
      mm(1, 0, a, b0);
      __builtin_amdgcn_sched_barrier(0);
      if (hf == 0) { if (more) wait_vmcnt<4>(); else wait_vmcnt<0>(); }
      else if (more) wait_vmcnt<4>();
      __builtin_amdgcn_s_barrier();
      __builtin_amdgcn_sched_barrier(0);
    }
  }

  // ---- epilogue ----
#pragma unroll
  for (int f = 0; f < 8; ++f) {
    const int r0 = bm + wm * 128 + f * 16 + (lane >> 4) * 4;
#pragma unroll
    for (int g = 0; g < 4; ++g) {
      const int c = bn + wn * 64 + g * 16 + (lane & 15);
      float bv = 0.f;
      if (MODE == 3) bv = bias[c];
#pragma unroll
      for (int r = 0; r < 4; ++r) {
        const size_t idx = (size_t)(r0 + r) * N + c;
        float v = acc[f][g][r];
        if (MODE == 3) v = gelu_f(v + bv);
        outB[idx] = (bf16)v;
      }
    }
  }
}

// ------------- 128x128 double-buffered GEMM, 256 threads, 2 blocks/CU -------------
// MODE 0: out bf16 | 1: +res(f32)->bf16 | 2: +res(f32)->f32 | 3: +bias,gelu->bf16
// MODE 4: +bias+res(f32)->f32
template <int MODE>
__global__ __launch_bounds__(256, 2) void gemm128(
    const bf16* __restrict__ A, const bf16* __restrict__ Bw,
    int M, int N, int K,
    const float* __restrict__ bias, const float* __restrict__ res,
    float* __restrict__ outF, bf16* __restrict__ outB) {
  constexpr int BM = 128, BN = 128;
  __shared__ __align__(16) bf16 As[2][BM * 64];   // 32 KB
  __shared__ __align__(16) bf16 Bs[2][BN * 64];   // 32 KB

  const int tid = threadIdx.x;
  const int lane = tid & 63, wid = tid >> 6;
  const int wm = wid >> 1, wn = wid & 1;

  int bid = blockIdx.x;
  const int nwg = gridDim.x;
  bid = (bid & 7) * (nwg >> 3) + (bid >> 3);   // XCD swizzle (nwg % 8 == 0)
  const int nbx = N / BN;
  const int bm = (bid / nbx) * BM, bn = (bid % nbx) * BN;
  const int NT = K >> 6;

  const int srow = tid >> 3;                       // 0..31
  const int scol = ((tid & 7) ^ (srow & 7)) * 8;
  const bf16* Ag = A  + (size_t)(bm + srow) * K + scol;
  const bf16* Bg = Bw + (size_t)(bn + srow) * K + scol;

  f32x4 acc[4][4] = {};
  const int lr = lane & 15, uo = lane >> 4;

  auto stA = [&](int buf, int t) {
#pragma unroll
    for (int c = 0; c < 4; ++c)
      gload16(Ag + ((size_t)(c * 32) * K + (size_t)t * 64),
              (char*)(&As[buf][0]) + c * 4096 + wid * 1024);
  };
  auto stB = [&](int buf, int t) {
#pragma unroll
    for (int c = 0; c < 4; ++c)
      gload16(Bg + ((size_t)(c * 32) * K + (size_t)t * 64),
              (char*)(&Bs[buf][0]) + c * 4096 + wid * 1024);
  };

  stA(0, 0); stB(0, 0);
  stA(1, 1); stB(1, 1);
  wait_vmcnt<8>();
  __builtin_amdgcn_s_barrier();

  bf16x8 a[4][2], b[4][2];

  for (int t = 0; t < NT; ++t) {
    const int cur = t & 1;
    const bf16* Asb = &As[cur][0];
    const bf16* Bsb = &Bs[cur][0];

#pragma unroll
    for (int i = 0; i < 4; ++i)
#pragma unroll
      for (int kh = 0; kh < 2; ++kh) {
        const int r = wm * 64 + i * 16 + lr;
        const int u = (kh * 4 + uo) ^ (lr & 7);
        a[i][kh] = *(const bf16x8*)&Asb[r * 64 + u * 8];
      }
#pragma unroll
    for (int j = 0; j < 4; ++j)
#pragma unroll
      for (int kh = 0; kh < 2; ++kh) {
        const int r = wn * 64 + j * 16 + lr;
        const int u = (kh * 4 + uo) ^ (lr & 7);
        b[j][kh] = *(const bf16x8*)&Bsb[r * 64 + u * 8];
      }
    wait_lgkm0();
    __builtin_amdgcn_sched_barrier(0);
    __builtin_amdgcn_s_barrier();
    __builtin_amdgcn_sched_barrier(0);

    if (t + 2 < NT) { stA(cur, t + 2); stB(cur, t + 2); }
    __builtin_amdgcn_sched_barrier(0);

    __builtin_amdgcn_s_setprio(1);
#pragma unroll
    for (int i = 0; i < 4; ++i)
#pragma unroll
      for (int j = 0; j < 4; ++j) {
        acc[i][j] = __builtin_amdgcn_mfma_f32_16x16x32_bf16(a[i][0], b[j][0], acc[i][j], 0, 0, 0);
        acc[i][j] = __builtin_amdgcn_mfma_f32_16x16x32_bf16(a[i][1], b[j][1], acc[i][j], 0, 0, 0);
      }
    __builtin_amdgcn_s_setprio(0);
    __builtin_amdgcn_sched_barrier(0);

    if (t < NT - 2) wait_vmcnt<8>();
    else            wait_vmcnt<0>();
    __builtin_amdgcn_s_barrier();
    __builtin_amdgcn_sched_barrier(0);
  }

#pragma unroll
  for (int f = 0; f < 4; ++f) {
    const int r0 = bm + wm * 64 + f * 16 + (lane >> 4) * 4;
#pragma unroll
    for (int g = 0; g < 4; ++g) {
      const int c = bn + wn * 64 + g * 16 + (lane & 15);
      float bv = 0.f;
      if (MODE == 3 || MODE == 4) bv = bias[c];
#pragma unroll
      for (int r = 0; r < 4; ++r) {
        const size_t idx = (size_t)(r0 + r) * N + c;
        float v = acc[f][g][r];
        if (MODE == 1 || MODE == 2) v += res[idx];
        if (MODE == 3) v = gelu_f(v + bv);
        if (MODE == 4) v += bv + res[idx];
        if (MODE == 0 || MODE == 1 || MODE == 3) outB[idx] = (bf16)v;
        else outF[idx] = v;
      }
    }
  }
}

// ------- fused Performer chunk-sums + segment scan (block = 1 segment) -------
__global__ __launch_bounds__(512) void perf_cs(
    const bf16* __restrict__ kmat, const bf16* __restrict__ vmat, int ld,
    const float* __restrict__ omega, float* __restrict__ CS,
    float* __restrict__ segtot) {
  const int tid = threadIdx.x;
  const int bh = blockIdx.y, b = bh >> 4, h = bh & 15;
  const int seg = blockIdx.x;
  const int s0 = seg * 512;
  __shared__ __align__(16) bf16 vs[512][64];   // XOR-swizzled, 64 KB
  __shared__ float kps[512][8];                // 16 KB
  __shared__ float oms[448];

  {
    const bf16* vb = vmat + ((size_t)(b * Sq + s0)) * ld + h * 64;
#pragma unroll
    for (int p = 0; p < 8; ++p) {
      const int row = p * 64 + (tid >> 3), c16 = (tid & 7) * 8;
      *(uint4*)&vs[row][c16 ^ ((row & 7) * 8)] =
          *(const uint4*)&vb[(size_t)row * ld + c16];
    }
  }
  if (tid < 448) oms[tid] = omega[tid];
  __syncthreads();

  {
    const int row = tid;
    const bf16* kr = kmat + ((size_t)(b * Sq + s0 + row)) * ld + h * 64;
    bf16x8 kv[8];
#pragma unroll
    for (int q = 0; q < 8; ++q) kv[q] = *(const bf16x8*)&kr[q * 8];
    float f[NB];
#pragma unroll
    for (int n = 0; n < NB; ++n) f[n] = 0.f;
#pragma unroll
    for (int d = 0; d < 64; ++d) {
      const float kd = (float)kv[d >> 3][d & 7];
#pragma unroll
      for (int n = 0; n < NB; ++n) f[n] += kd * oms[n * 64 + d];
    }
    float sum = 1e-6f, e[NB];
#pragma unroll
    for (int n = 0; n < NB; ++n) { e[n] = __expf(-0.5f * f[n] * f[n]); sum += e[n]; }
    const float inv = 1.f / sum;
#pragma unroll
    for (int n = 0; n < NB; ++n) kps[row][n] = e[n] * inv;
    kps[row][7] = 0.f;
  }
  __syncthreads();

  if (tid < CSW) {
    const int comp = tid;
    float* outb = CS + ((size_t)bh * NCH + seg * 128) * CSW;
    float r = 0.f;
    if (comp < 8) {
      for (int c = 0; c < 128; ++c) {
        if (comp < 7)
          r += kps[4*c][comp] + kps[4*c+1][comp] + kps[4*c+2][comp] + kps[4*c+3][comp];
        outb[(size_t)c * CSW + comp] = r;
      }
    } else if (comp < 456) {
      const int n = (comp - 8) >> 6, d = (comp - 8) & 63;
      for (int c = 0; c < 128; ++c) {
#pragma unroll
        for (int i = 0; i < 4; ++i) {
          const int row = 4 * c + i;
          r += kps[row][n] * (float)vs[row][d ^ ((row & 7) * 8)];
        }
        outb[(size_t)c * CSW + comp] = r;
      }
    } else {
      for (int c = 0; c < 128; ++c) outb[(size_t)c * CSW + comp] = 0.f;
    }
    segtot[((size_t)bh * 8 + seg) * CSW + comp] = r;
  }
}

// ---------------- exclusive scan of the 8 segment totals ----------------
__global__ __launch_bounds__(256) void perf_scan2(float* __restrict__ segtot) {
  const int bh = blockIdx.x;
  const int c0 = threadIdx.x;
  float run0 = 0.f, run1 = 0.f;
#pragma unroll
  for (int s = 0; s < 8; ++s) {
    float* st = segtot + ((size_t)bh * 8 + s) * CSW;
    float t0 = st[c0]; st[c0] = run0; run0 += t0;
    if (c0 + 256 < CSW) { float t1 = st[c0 + 256]; st[c0 + 256] = run1; run1 += t1; }
  }
}

// ---------------- Performer output ----------------
__global__ __launch_bounds__(256) void perf_out(
    const bf16* __restrict__ qmat, int ldq, const float* __restrict__ omega,
    const float* __restrict__ CS, const float* __restrict__ segtot,
    bf16* __restrict__ attn) {
  const int tid = threadIdx.x;
  const int bh = blockIdx.y, b = bh >> 4, h = bh & 15;
  const int s0 = blockIdx.x * 128;
  const int cg0 = s0 >> 2;
  const int seg = cg0 >> 7;
  __shared__ __align__(16) float Ps[32 * CSW];
  __shared__ float qps[128][8];
  __shared__ float oms[NB * 64];

  {
    const float* src = CS + ((size_t)bh * NCH + cg0) * CSW;
    const float* off = segtot + ((size_t)bh * 8 + seg) * CSW;
    for (int i = tid; i < 32 * CSW / 4; i += 256) {
      f32x4 a = *(const f32x4*)&src[i * 4];
      f32x4 o = *(const f32x4*)&off[(i % (CSW / 4)) * 4];
      a += o;
      *(f32x4*)&Ps[i * 4] = a;
    }
  }
  if (tid < 224) { oms[tid] = omega[tid]; oms[tid + 224] = omega[tid + 224]; }
  __syncthreads();
  {
    const int p = tid >> 1, half = tid & 1;
    const bf16* qr = qmat + ((size_t)(b * Sq + s0 + p)) * ldq + h * 64 + half * 32;
    bf16x8 qv[4];
#pragma unroll
    for (int q = 0; q < 4; ++q) qv[q] = *(const bf16x8*)&qr[q * 8];
    float f[NB];
#pragma unroll
    for (int n = 0; n < NB; ++n) f[n] = 0.f;
#pragma unroll
    for (int d = 0; d < 32; ++d) {
      float qd = (float)qv[d >> 3][d & 7];
#pragma unroll
      for (int n = 0; n < NB; ++n) f[n] += qd * oms[n * 64 + half * 32 + d];
    }
    float sum = 1e-6f;
    float e[NB];
#pragma unroll
    for (int n = 0; n < NB; ++n) {
      float full = f[n] + __shfl_xor(f[n], 1);
      e[n] = __expf(-0.5f * full * full);
      sum += e[n];
    }
    float inv = 1.f / sum;
    if (half == 0) {
      float den = 1e-6f;
      const float* Pr = &Ps[(p >> 2) * CSW];
#pragma unroll
      for (int n = 0; n < NB; ++n) {
        float qn = e[n] * inv;
        qps[p][n] = qn;
        den += qn * Pr[n];
      }
      qps[p][7] = 1.f / den;
    }
  }
  __syncthreads();
  {
    const int d = tid & 63, w = tid >> 6;
    for (int qq = w; qq < 128; qq += 4) {
      const float* Pr = &Ps[(qq >> 2) * CSW + 8 + d];
      float num = 0.f;
#pragma unroll
      for (int n = 0; n < NB; ++n) num += qps[qq][n] * Pr[n * 64];
      attn[((size_t)(b * Sq + s0 + qq)) * Dm + h * 64 + d] = (bf16)(num * qps[qq][7]);
    }
  }
}

// ---------------------------------------------------------------------------
extern "C" void kernel_launch(void* const* d_in, const int* in_sizes, int n_in,
                              void* d_out, int out_size, void* d_ws, size_t ws_size,
                              hipStream_t stream) {
  const float* x    = (const float*)d_in[0];
  const float* lto  = (const float*)d_in[1];
  const float* w_s[4] = {(const float*)d_in[2], (const float*)d_in[3],
                         (const float*)d_in[4], (const float*)d_in[5]};
  const float* w_c[4] = {(const float*)d_in[6], (const float*)d_in[7],
                         (const float*)d_in[8], (const float*)d_in[9]};
  const float* omega_s = (const float*)d_in[10];
  const float* omega_c = (const float*)d_in[11];
  const float* w1 = (const float*)d_in[12];
  const float* b1 = (const float*)d_in[13];
  const float* w2 = (const float*)d_in[14];
  const float* b2 = (const float*)d_in[15];
  const float* ln_a[3] = {(const float*)d_in[16], (const float*)d_in[18], (const float*)d_in[20]};
  const float* ln_b[3] = {(const float*)d_in[17], (const float*)d_in[19], (const float*)d_in[21]};

  char* ws = (char*)d_ws;
  size_t off = 0;
  auto alloc = [&](size_t bytes) -> char* {
    char* p = ws + off;
    off += (bytes + 255) & ~(size_t)255;
    return p;
  };

  const size_t actB = (size_t)Mrows * Dm * sizeof(bf16);     // 16 MiB
  const size_t MB32 = (size_t)Mrows * 2048 * sizeof(bf16);   // 32 MiB

  bf16* wqkv = (bf16*)alloc((size_t)3072 * 1024 * 2);
  bf16* wo_sb = (bf16*)alloc((size_t)1024 * 1024 * 2);
  bf16* wq_cb = (bf16*)alloc((size_t)1024 * 1024 * 2);
  bf16* wkv  = (bf16*)alloc((size_t)2048 * 1024 * 2);
  bf16* wo_cb = (bf16*)alloc((size_t)1024 * 1024 * 2);
  bf16* w1b = (bf16*)alloc((size_t)Dff * Dm * 2);
  bf16* w2b = (bf16*)alloc((size_t)Dff * Dm * 2);
  bf16* xnb  = (bf16*)alloc(actB);
  char* pool = alloc((size_t)Mrows * Dff * 2);               // 64 MiB shared pool
  bf16* qkvb = (bf16*)pool;                                  // 48 MiB (phase 1)
  bf16* kvb  = (bf16*)pool;                                  // 32 MiB (phase 2)
  bf16* qb   = (bf16*)(pool + MB32);                         // 16 MiB (phase 2)
  bf16* hb   = (bf16*)pool;                                  // 64 MiB (phase 3)
  bf16* attnb= (bf16*)alloc(actB);
  bf16* x2b  = (bf16*)alloc(actB);
  bf16* ln1b = (bf16*)alloc(actB);
  float* lto2 = (float*)alloc((size_t)Mrows * Dm * 4);
  float* CSb  = (float*)alloc((size_t)32 * NCH * CSW * 4);
  float* stb  = (float*)alloc((size_t)32 * 8 * CSW * 4);
  bf16* fnb = xnb;   // xnb dead after QKV_s GEMM

  // ---- batched weight conversion ----
  {
    CvtA a;
    const float* srcs[10] = {w_s[0], w_s[1], w_s[2], w_s[3], w_c[0],
                             w_c[1], w_c[2], w_c[3], w1, w2};
    bf16* dsts[10] = {wqkv, wqkv + 1048576, wqkv + 2097152, wo_sb, wq_cb,
                      wkv, wkv + 1048576, wo_cb, w1b, w2b};
    const int SM = 262144, LG = 1048576;
    int st = 0;
    for (int i = 0; i < 10; ++i) {
      a.s[i] = srcs[i]; a.d[i] = dsts[i]; a.start[i] = st;
      st += (i < 8) ? SM : LG;
    }
    a.start[10] = st;
    cvt10<<<st / 256, 256, 0, stream>>>(a);
  }

  dim3 gperf(Sq / 128, Bq * 16);
  dim3 gseg(8, Bq * 16);
  const int gQKV = (Mrows / 256) * (3072 / 256);   // 384
  const int gKV  = (Mrows / 256) * (2048 / 256);   // 256
  const int gFF1 = (Mrows / 256) * (4096 / 256);   // 512
  const int gN1k = (Mrows / 128) * (1024 / 128);   // 512

  // --- self performer on x ---
  ln_kernel<<<Mrows, 256, 0, stream>>>(x, ln_a[0], ln_b[0], xnb);
  gemm256<0><<<gQKV, 512, 0, stream>>>(xnb, wqkv, Mrows, 3072, 1024, nullptr, qkvb);
  perf_cs<<<gseg, 512, 0, stream>>>(qkvb + 1024, qkvb + 2048, 3072, omega_s, CSb, stb);
  perf_scan2<<<32, 256, 0, stream>>>(stb);
  perf_out<<<gperf, 256, 0, stream>>>(qkvb, 3072, omega_s, CSb, stb, attnb);
  gemm128<1><<<gN1k, 256, 0, stream>>>(attnb, wo_sb, Mrows, 1024, 1024, nullptr, x, nullptr, x2b);

  // --- cross performer: q from LN(lto), k/v from updated x ---
  ln_kernel<<<Mrows, 256, 0, stream>>>(lto, ln_a[1], ln_b[1], ln1b);
  gemm128<0><<<gN1k, 256, 0, stream>>>(ln1b, wq_cb, Mrows, 1024, 1024, nullptr, nullptr, nullptr, qb);
  gemm256<0><<<gKV, 512, 0, stream>>>(x2b, wkv, Mrows, 2048, 1024, nullptr, kvb);
  perf_cs<<<gseg, 512, 0, stream>>>(kvb, kvb + 1024, 2048, omega_c, CSb, stb);
  perf_scan2<<<32, 256, 0, stream>>>(stb);
  perf_out<<<gperf, 256, 0, stream>>>(qb, 1024, omega_c, CSb, stb, attnb);
  gemm128<2><<<gN1k, 256, 0, stream>>>(attnb, wo_cb, Mrows, 1024, 1024, nullptr, lto, lto2, nullptr);

  // --- FFN ---
  ln_kernel<<<Mrows, 256, 0, stream>>>(lto2, ln_a[2], ln_b[2], fnb);
  gemm256<3><<<gFF1, 512, 0, stream>>>(fnb, w1b, Mrows, 4096, 1024, b1, hb);
  gemm128<4><<<gN1k, 256, 0, stream>>>(hb, w2b, Mrows, 1024, 4096, b2, lto2, (float*)d_out, nullptr);
}